// Round 1
// baseline (702.531 us; speedup 1.0000x reference)
//
#include <hip/hip_runtime.h>

#define NODES 100000
#define EDGES 1600000
// IN_F = HID_F = 128, OUT_F = 64

// ---------------- CSR build ----------------

__global__ void hist_kernel(const int* __restrict__ dst, int* __restrict__ deg) {
    int e = blockIdx.x * 256 + threadIdx.x;
    if (e < EDGES) atomicAdd(&deg[dst[e]], 1);
}

__global__ void scanA_kernel(const int* __restrict__ deg, int* __restrict__ incl,
                             int* __restrict__ part) {
    __shared__ int sh[1024];
    int i = blockIdx.x * 1024 + threadIdx.x;
    int v = (i < NODES) ? deg[i] : 0;
    sh[threadIdx.x] = v;
    __syncthreads();
    for (int off = 1; off < 1024; off <<= 1) {
        int x = (threadIdx.x >= off) ? sh[threadIdx.x - off] : 0;
        __syncthreads();
        sh[threadIdx.x] += x;
        __syncthreads();
    }
    if (i < NODES) incl[i] = sh[threadIdx.x];
    if (threadIdx.x == 1023) part[blockIdx.x] = sh[1023];
}

__global__ void scanB_kernel(int* __restrict__ part, int* __restrict__ row_ptr, int nblk) {
    __shared__ int sh[128];
    int t = threadIdx.x;
    int v = (t < nblk) ? part[t] : 0;
    sh[t] = v;
    __syncthreads();
    for (int off = 1; off < 128; off <<= 1) {
        int x = (t >= off) ? sh[t - off] : 0;
        __syncthreads();
        sh[t] += x;
        __syncthreads();
    }
    if (t < nblk) part[t] = sh[t] - v;  // exclusive block offsets
    if (t == 127) row_ptr[NODES] = sh[127];
}

__global__ void scanC_kernel(const int* __restrict__ deg, int* __restrict__ row_ptr,
                             int* __restrict__ cursor, const int* __restrict__ part) {
    int i = blockIdx.x * 1024 + threadIdx.x;
    if (i < NODES) {
        int excl = row_ptr[i] - deg[i] + part[blockIdx.x];
        row_ptr[i] = excl;
        cursor[i] = excl;
    }
}

__global__ void scatter_kernel(const int* __restrict__ src, const int* __restrict__ dst,
                               int* __restrict__ cursor, int* __restrict__ src_sorted) {
    int e = blockIdx.x * 256 + threadIdx.x;
    if (e < EDGES) {
        int p = atomicAdd(&cursor[dst[e]], 1);
        src_sorted[p] = src[e];
    }
}

// ---------------- Mean aggregation (gather via CSR) ----------------
// One wave (64 lanes) per node. 128-feature variant: float2 per lane.

__global__ void agg_mean128_kernel(const float* __restrict__ x, const int* __restrict__ row_ptr,
                                   const int* __restrict__ srcs, float* __restrict__ out) {
    int w = (blockIdx.x * blockDim.x + threadIdx.x) >> 6;
    int lane = threadIdx.x & 63;
    if (w >= NODES) return;
    int beg = row_ptr[w], end = row_ptr[w + 1];
    float ax0 = 0.f, ay0 = 0.f, ax1 = 0.f, ay1 = 0.f;
    int e = beg;
    for (; e + 2 <= end; e += 2) {
        int s0 = srcs[e], s1 = srcs[e + 1];
        float2 v0 = *reinterpret_cast<const float2*>(x + (size_t)s0 * 128 + lane * 2);
        float2 v1 = *reinterpret_cast<const float2*>(x + (size_t)s1 * 128 + lane * 2);
        ax0 += v0.x; ay0 += v0.y;
        ax1 += v1.x; ay1 += v1.y;
    }
    if (e < end) {
        int s0 = srcs[e];
        float2 v0 = *reinterpret_cast<const float2*>(x + (size_t)s0 * 128 + lane * 2);
        ax0 += v0.x; ay0 += v0.y;
    }
    float inv = 1.0f / fmaxf((float)(end - beg), 1.0f);
    float2 r;
    r.x = (ax0 + ax1) * inv;
    r.y = (ay0 + ay1) * inv;
    *reinterpret_cast<float2*>(out + (size_t)w * 128 + lane * 2) = r;
}

// 64-feature variant: one float per lane.
__global__ void agg_mean64_kernel(const float* __restrict__ x, const int* __restrict__ row_ptr,
                                  const int* __restrict__ srcs, float* __restrict__ out) {
    int w = (blockIdx.x * blockDim.x + threadIdx.x) >> 6;
    int lane = threadIdx.x & 63;
    if (w >= NODES) return;
    int beg = row_ptr[w], end = row_ptr[w + 1];
    float a0 = 0.f, a1 = 0.f;
    int e = beg;
    for (; e + 2 <= end; e += 2) {
        int s0 = srcs[e], s1 = srcs[e + 1];
        a0 += x[(size_t)s0 * 64 + lane];
        a1 += x[(size_t)s1 * 64 + lane];
    }
    if (e < end) a0 += x[(size_t)srcs[e] * 64 + lane];
    float inv = 1.0f / fmaxf((float)(end - beg), 1.0f);
    out[(size_t)w * 64 + lane] = (a0 + a1) * inv;
}

// ---------------- f32 GEMM (K=128 fixed), fused epilogue ----------------
// C[M x NCOL] = A0@W0 (+ A1@W1) (+ bias) (+ add2) (relu?)
// Block: 256 threads. Thread covers 4 consecutive cols x 4 rows.

template <int NCOL, bool DUAL, bool RELU, bool BIAS, bool ADD2>
__global__ __launch_bounds__(256) void gemm_kernel(
    const float* __restrict__ A0, const float* __restrict__ W0,
    const float* __restrict__ A1, const float* __restrict__ W1,
    const float* __restrict__ bias, const float* __restrict__ add2,
    float* __restrict__ C, int M) {
    constexpr int CL = NCOL / 4;   // col-lane count
    constexpr int RG = 256 / CL;   // row groups
    constexpr int TM = RG * 4;     // tile rows
    __shared__ float Alds[TM * 132];  // row-major, stride 132 (pad 4 keeps 16B align)

    int t = threadIdx.x;
    int cx = t % CL;
    int ry = t / CL;
    int row0 = blockIdx.x * TM;

    float4 acc[4];
#pragma unroll
    for (int i = 0; i < 4; ++i) acc[i] = make_float4(0.f, 0.f, 0.f, 0.f);

    auto stage = [&](const float* __restrict__ A) {
        for (int f = t; f < TM * 32; f += 256) {
            int r = f >> 5;
            int c4 = (f & 31) << 2;
            int gr = row0 + r;
            float4 v = make_float4(0.f, 0.f, 0.f, 0.f);
            if (gr < M) v = *reinterpret_cast<const float4*>(A + (size_t)gr * 128 + c4);
            *reinterpret_cast<float4*>(&Alds[r * 132 + c4]) = v;
        }
    };

    auto mac = [&](const float* __restrict__ W) {
        for (int kb = 0; kb < 128; kb += 4) {
            float4 w0 = *reinterpret_cast<const float4*>(W + (size_t)(kb + 0) * NCOL + cx * 4);
            float4 w1 = *reinterpret_cast<const float4*>(W + (size_t)(kb + 1) * NCOL + cx * 4);
            float4 w2 = *reinterpret_cast<const float4*>(W + (size_t)(kb + 2) * NCOL + cx * 4);
            float4 w3 = *reinterpret_cast<const float4*>(W + (size_t)(kb + 3) * NCOL + cx * 4);
#pragma unroll
            for (int i = 0; i < 4; ++i) {
                float4 a = *reinterpret_cast<const float4*>(&Alds[(ry * 4 + i) * 132 + kb]);
                acc[i].x += a.x * w0.x + a.y * w1.x + a.z * w2.x + a.w * w3.x;
                acc[i].y += a.x * w0.y + a.y * w1.y + a.z * w2.y + a.w * w3.y;
                acc[i].z += a.x * w0.z + a.y * w1.z + a.z * w2.z + a.w * w3.z;
                acc[i].w += a.x * w0.w + a.y * w1.w + a.z * w2.w + a.w * w3.w;
            }
        }
    };

    stage(A0);
    __syncthreads();
    mac(W0);
    if (DUAL) {
        __syncthreads();
        stage(A1);
        __syncthreads();
        mac(W1);
    }

    float4 b4 = make_float4(0.f, 0.f, 0.f, 0.f);
    if (BIAS) b4 = *reinterpret_cast<const float4*>(bias + cx * 4);
#pragma unroll
    for (int i = 0; i < 4; ++i) {
        int r = row0 + ry * 4 + i;
        if (r < M) {
            float4 v = acc[i];
            if (BIAS) { v.x += b4.x; v.y += b4.y; v.z += b4.z; v.w += b4.w; }
            if (ADD2) {
                float4 g = *reinterpret_cast<const float4*>(add2 + (size_t)r * NCOL + cx * 4);
                v.x += g.x; v.y += g.y; v.z += g.z; v.w += g.w;
            }
            if (RELU) {
                v.x = fmaxf(v.x, 0.f); v.y = fmaxf(v.y, 0.f);
                v.z = fmaxf(v.z, 0.f); v.w = fmaxf(v.w, 0.f);
            }
            *reinterpret_cast<float4*>(C + (size_t)r * NCOL + cx * 4) = v;
        }
    }
}

// ---------------- launch ----------------

extern "C" void kernel_launch(void* const* d_in, const int* in_sizes, int n_in,
                              void* d_out, int out_size, void* d_ws, size_t ws_size,
                              hipStream_t stream) {
    const float* features = (const float*)d_in[0];
    const int* esrc = (const int*)d_in[1];
    const int* edst = (const int*)d_in[2];
    const float* W1s = (const float*)d_in[3];
    const float* W1n = (const float*)d_in[4];
    const float* b1  = (const float*)d_in[5];
    const float* W2s = (const float*)d_in[6];
    const float* W2n = (const float*)d_in[7];
    const float* b2  = (const float*)d_in[8];
    float* out = (float*)d_out;

    char* ws = (char*)d_ws;
    size_t off = 0;
    auto alloc = [&](size_t bytes) {
        void* p = ws + off;
        off += (bytes + 255) & ~(size_t)255;
        return p;
    };
    int* deg        = (int*)alloc((size_t)NODES * 4);
    int* row_ptr    = (int*)alloc((size_t)(NODES + 1) * 4);
    int* cursor     = (int*)alloc((size_t)NODES * 4);
    int* part       = (int*)alloc(128 * 4);
    int* src_sorted = (int*)alloc((size_t)EDGES * 4);
    float* agg1     = (float*)alloc((size_t)NODES * 128 * 4);
    float* x1       = (float*)alloc((size_t)NODES * 128 * 4);
    float* x1h  = agg1;                        // reuse agg1 after gemm1 consumes it
    float* agg2 = agg1 + (size_t)NODES * 64;   // second half of agg1 buffer

    hipMemsetAsync(deg, 0, (size_t)NODES * 4, stream);
    hist_kernel<<<(EDGES + 255) / 256, 256, 0, stream>>>(edst, deg);
    int nblk = (NODES + 1023) / 1024;  // 98
    scanA_kernel<<<nblk, 1024, 0, stream>>>(deg, row_ptr, part);
    scanB_kernel<<<1, 128, 0, stream>>>(part, row_ptr, nblk);
    scanC_kernel<<<nblk, 1024, 0, stream>>>(deg, row_ptr, cursor, part);
    scatter_kernel<<<(EDGES + 255) / 256, 256, 0, stream>>>(esrc, edst, cursor, src_sorted);

    // layer 1: agg1 = mean-neigh(features); x1 = relu(feat@W1s + agg1@W1n + b1)
    agg_mean128_kernel<<<(NODES * 64 + 255) / 256, 256, 0, stream>>>(features, row_ptr, src_sorted, agg1);
    gemm_kernel<128, true, true, true, false><<<(NODES + 31) / 32, 256, 0, stream>>>(
        features, W1s, agg1, W1n, b1, nullptr, x1, NODES);

    // layer 2 (projected-first): x1h = x1@W2n; agg2 = mean-neigh(x1h);
    // out = x1@W2s + agg2 + b2
    gemm_kernel<64, false, false, false, false><<<(NODES + 63) / 64, 256, 0, stream>>>(
        x1, W2n, nullptr, nullptr, nullptr, nullptr, x1h, NODES);
    agg_mean64_kernel<<<(NODES * 64 + 255) / 256, 256, 0, stream>>>(x1h, row_ptr, src_sorted, agg2);
    gemm_kernel<64, false, false, true, true><<<(NODES + 63) / 64, 256, 0, stream>>>(
        x1, W2s, nullptr, nullptr, b2, agg2, out, NODES);
}

// Round 2
// 541.731 us; speedup vs baseline: 1.2968x; 1.2968x over previous
//
#include <hip/hip_runtime.h>

#define NODES 100000
#define EDGES 1600000
// IN_F = HID_F = 128, OUT_F = 64

using bf16x8 = __attribute__((ext_vector_type(8))) short;
using f32x4  = __attribute__((ext_vector_type(4))) float;

__device__ __forceinline__ unsigned short f2b(float f) {
    unsigned u = __builtin_bit_cast(unsigned, f);
    unsigned r = (u + 0x7FFFu + ((u >> 16) & 1u)) >> 16;
    return (unsigned short)r;
}
__device__ __forceinline__ float blo(unsigned u) {
    return __builtin_bit_cast(float, u << 16);
}
__device__ __forceinline__ float bhi(unsigned u) {
    return __builtin_bit_cast(float, u & 0xFFFF0000u);
}

// ---------------- CSR build ----------------

__global__ void hist_kernel(const int* __restrict__ dst, int* __restrict__ deg) {
    int e = blockIdx.x * 256 + threadIdx.x;
    if (e < EDGES) atomicAdd(&deg[dst[e]], 1);
}

__global__ void scanA_kernel(const int* __restrict__ deg, int* __restrict__ incl,
                             int* __restrict__ part) {
    __shared__ int sh[1024];
    int i = blockIdx.x * 1024 + threadIdx.x;
    int v = (i < NODES) ? deg[i] : 0;
    sh[threadIdx.x] = v;
    __syncthreads();
    for (int off = 1; off < 1024; off <<= 1) {
        int x = (threadIdx.x >= off) ? sh[threadIdx.x - off] : 0;
        __syncthreads();
        sh[threadIdx.x] += x;
        __syncthreads();
    }
    if (i < NODES) incl[i] = sh[threadIdx.x];
    if (threadIdx.x == 1023) part[blockIdx.x] = sh[1023];
}

__global__ void scanB_kernel(int* __restrict__ part, int* __restrict__ row_ptr, int nblk) {
    __shared__ int sh[128];
    int t = threadIdx.x;
    int v = (t < nblk) ? part[t] : 0;
    sh[t] = v;
    __syncthreads();
    for (int off = 1; off < 128; off <<= 1) {
        int x = (t >= off) ? sh[t - off] : 0;
        __syncthreads();
        sh[t] += x;
        __syncthreads();
    }
    if (t < nblk) part[t] = sh[t] - v;  // exclusive block offsets
    if (t == 127) row_ptr[NODES] = sh[127];
}

__global__ void scanC_kernel(const int* __restrict__ deg, int* __restrict__ row_ptr,
                             int* __restrict__ cursor, const int* __restrict__ part) {
    int i = blockIdx.x * 1024 + threadIdx.x;
    if (i < NODES) {
        int excl = row_ptr[i] - deg[i] + part[blockIdx.x];
        row_ptr[i] = excl;
        cursor[i] = excl;
    }
}

__global__ void scatter_kernel(const int* __restrict__ src, const int* __restrict__ dst,
                               int* __restrict__ cursor, int* __restrict__ src_sorted) {
    int e = blockIdx.x * 256 + threadIdx.x;
    if (e < EDGES) {
        int p = atomicAdd(&cursor[dst[e]], 1);
        src_sorted[p] = src[e];
    }
}

// ---------------- conversions ----------------

__global__ void f2b_kernel(const float* __restrict__ in, unsigned short* __restrict__ out, int n4) {
    int i = blockIdx.x * 256 + threadIdx.x;
    if (i < n4) {
        float4 v = reinterpret_cast<const float4*>(in)[i];
        uint2 o;
        o.x = (unsigned)f2b(v.x) | ((unsigned)f2b(v.y) << 16);
        o.y = (unsigned)f2b(v.z) | ((unsigned)f2b(v.w) << 16);
        reinterpret_cast<uint2*>(out)[i] = o;
    }
}

// transpose+convert weights: W[k][n] f32 -> Wt[n][k] bf16 (k stride 128)
__global__ void wconv_kernel(const float* __restrict__ W1s, const float* __restrict__ W1n,
                             const float* __restrict__ W2s, const float* __restrict__ W2n,
                             unsigned short* __restrict__ Wt1s, unsigned short* __restrict__ Wt1n,
                             unsigned short* __restrict__ Wt2s, unsigned short* __restrict__ Wt2n) {
    int t = blockIdx.x * 256 + threadIdx.x;
    if (t < 16384) {
        int k = t >> 7, n = t & 127;
        Wt1s[n * 128 + k] = f2b(W1s[t]);
        Wt1n[n * 128 + k] = f2b(W1n[t]);
    }
    if (t < 8192) {
        int k = t >> 6, n = t & 63;
        Wt2s[n * 128 + k] = f2b(W2s[t]);
        Wt2n[n * 128 + k] = f2b(W2n[t]);
    }
}

// ---------------- Mean aggregation (gather via CSR), bf16 ----------------
// One wave per node; lane covers 2 features (4B packed bf16x2 loads).

__global__ void agg128_bf16(const unsigned short* __restrict__ xb, const int* __restrict__ row_ptr,
                            const int* __restrict__ srcs, unsigned short* __restrict__ out) {
    int w = (blockIdx.x * blockDim.x + threadIdx.x) >> 6;
    int lane = threadIdx.x & 63;
    if (w >= NODES) return;
    int beg = row_ptr[w], end = row_ptr[w + 1];
    float s0a = 0.f, s0b = 0.f, s1a = 0.f, s1b = 0.f;
    int e = beg;
    for (; e + 2 <= end; e += 2) {
        int n0 = srcs[e], n1 = srcs[e + 1];
        unsigned u0 = *reinterpret_cast<const unsigned*>(xb + (size_t)n0 * 128 + lane * 2);
        unsigned u1 = *reinterpret_cast<const unsigned*>(xb + (size_t)n1 * 128 + lane * 2);
        s0a += blo(u0); s0b += bhi(u0);
        s1a += blo(u1); s1b += bhi(u1);
    }
    if (e < end) {
        unsigned u0 = *reinterpret_cast<const unsigned*>(xb + (size_t)srcs[e] * 128 + lane * 2);
        s0a += blo(u0); s0b += bhi(u0);
    }
    float inv = 1.0f / fmaxf((float)(end - beg), 1.0f);
    unsigned o = (unsigned)f2b((s0a + s1a) * inv) | ((unsigned)f2b((s0b + s1b) * inv) << 16);
    *reinterpret_cast<unsigned*>(out + (size_t)w * 128 + lane * 2) = o;
}

// half-wave per node; 64 features; adds mean into f32 out (in-place).
__global__ void agg64_add(const unsigned short* __restrict__ xh, const int* __restrict__ row_ptr,
                          const int* __restrict__ srcs, float* __restrict__ out) {
    int t = blockIdx.x * blockDim.x + threadIdx.x;
    int node = t >> 5;
    int l = t & 31;
    if (node >= NODES) return;
    int beg = row_ptr[node], end = row_ptr[node + 1];
    float s0a = 0.f, s0b = 0.f, s1a = 0.f, s1b = 0.f;
    int e = beg;
    for (; e + 2 <= end; e += 2) {
        int n0 = srcs[e], n1 = srcs[e + 1];
        unsigned u0 = *reinterpret_cast<const unsigned*>(xh + (size_t)n0 * 64 + l * 2);
        unsigned u1 = *reinterpret_cast<const unsigned*>(xh + (size_t)n1 * 64 + l * 2);
        s0a += blo(u0); s0b += bhi(u0);
        s1a += blo(u1); s1b += bhi(u1);
    }
    if (e < end) {
        unsigned u0 = *reinterpret_cast<const unsigned*>(xh + (size_t)srcs[e] * 64 + l * 2);
        s0a += blo(u0); s0b += bhi(u0);
    }
    float inv = 1.0f / fmaxf((float)(end - beg), 1.0f);
    float2 p = *reinterpret_cast<float2*>(out + (size_t)node * 64 + l * 2);
    p.x += (s0a + s1a) * inv;
    p.y += (s0b + s1b) * inv;
    *reinterpret_cast<float2*>(out + (size_t)node * 64 + l * 2) = p;
}

// ---------------- MFMA GEMMs (bf16 in, K=128) ----------------
// A-frag: A[m=lane&15][k=quad*8+j]; B-frag: B[k=quad*8+j][n=lane&15] from
// Wt[n][k] (transposed weights); C/D: col=lane&15, row=quad*4+reg.

// Layer 1: x1 = relu(feat@W1s + agg@W1n + b1), out bf16 [M][128].
__global__ __launch_bounds__(256) void gemm1_mfma(
    const unsigned short* __restrict__ feat, const unsigned short* __restrict__ agg,
    const unsigned short* __restrict__ Wt0, const unsigned short* __restrict__ Wt1,
    const float* __restrict__ bias, unsigned short* __restrict__ x1, int M) {
    int wid = threadIdx.x >> 6, lane = threadIdx.x & 63;
    int l15 = lane & 15, quad = lane >> 4;
    int rb = blockIdx.x * 128 + wid * 32;  // wave covers 32 rows (2 groups of 16)

    f32x4 acc[2][8];
#pragma unroll
    for (int rg = 0; rg < 2; ++rg)
#pragma unroll
        for (int nt = 0; nt < 8; ++nt) acc[rg][nt] = {0.f, 0.f, 0.f, 0.f};

#pragma unroll
    for (int k0 = 0; k0 < 128; k0 += 32) {
        bf16x8 a0[2], a1[2];
#pragma unroll
        for (int rg = 0; rg < 2; ++rg) {
            int r = rb + rg * 16 + l15;
            if (r >= M) r = M - 1;
            a0[rg] = *reinterpret_cast<const bf16x8*>(feat + (size_t)r * 128 + quad * 8 + k0);
            a1[rg] = *reinterpret_cast<const bf16x8*>(agg + (size_t)r * 128 + quad * 8 + k0);
        }
#pragma unroll
        for (int nt = 0; nt < 8; ++nt) {
            bf16x8 b0 = *reinterpret_cast<const bf16x8*>(Wt0 + (size_t)(nt * 16 + l15) * 128 + quad * 8 + k0);
            bf16x8 b1 = *reinterpret_cast<const bf16x8*>(Wt1 + (size_t)(nt * 16 + l15) * 128 + quad * 8 + k0);
#pragma unroll
            for (int rg = 0; rg < 2; ++rg) {
                acc[rg][nt] = __builtin_amdgcn_mfma_f32_16x16x32_bf16(a0[rg], b0, acc[rg][nt], 0, 0, 0);
                acc[rg][nt] = __builtin_amdgcn_mfma_f32_16x16x32_bf16(a1[rg], b1, acc[rg][nt], 0, 0, 0);
            }
        }
    }

#pragma unroll
    for (int nt = 0; nt < 8; ++nt) {
        int col = nt * 16 + l15;
        float bv = bias[col];
#pragma unroll
        for (int rg = 0; rg < 2; ++rg)
#pragma unroll
            for (int rr = 0; rr < 4; ++rr) {
                int row = rb + rg * 16 + quad * 4 + rr;
                if (row < M) {
                    float v = fmaxf(acc[rg][nt][rr] + bv, 0.f);
                    x1[(size_t)row * 128 + col] = f2b(v);
                }
            }
    }
}

// Layer 2 fused: x1h = x1@W2n (bf16 out), outp = x1@W2s + b2 (f32 out).
__global__ __launch_bounds__(256) void gemm2_mfma(
    const unsigned short* __restrict__ x1,
    const unsigned short* __restrict__ WtS, const unsigned short* __restrict__ WtN,
    const float* __restrict__ bias, unsigned short* __restrict__ x1h,
    float* __restrict__ outp, int M) {
    int wid = threadIdx.x >> 6, lane = threadIdx.x & 63;
    int l15 = lane & 15, quad = lane >> 4;
    int rb = blockIdx.x * 128 + wid * 32;

    f32x4 accS[2][4], accN[2][4];
#pragma unroll
    for (int rg = 0; rg < 2; ++rg)
#pragma unroll
        for (int nt = 0; nt < 4; ++nt) {
            accS[rg][nt] = {0.f, 0.f, 0.f, 0.f};
            accN[rg][nt] = {0.f, 0.f, 0.f, 0.f};
        }

#pragma unroll
    for (int k0 = 0; k0 < 128; k0 += 32) {
        bf16x8 a[2];
#pragma unroll
        for (int rg = 0; rg < 2; ++rg) {
            int r = rb + rg * 16 + l15;
            if (r >= M) r = M - 1;
            a[rg] = *reinterpret_cast<const bf16x8*>(x1 + (size_t)r * 128 + quad * 8 + k0);
        }
#pragma unroll
        for (int nt = 0; nt < 4; ++nt) {
            bf16x8 bS = *reinterpret_cast<const bf16x8*>(WtS + (size_t)(nt * 16 + l15) * 128 + quad * 8 + k0);
            bf16x8 bN = *reinterpret_cast<const bf16x8*>(WtN + (size_t)(nt * 16 + l15) * 128 + quad * 8 + k0);
#pragma unroll
            for (int rg = 0; rg < 2; ++rg) {
                accS[rg][nt] = __builtin_amdgcn_mfma_f32_16x16x32_bf16(a[rg], bS, accS[rg][nt], 0, 0, 0);
                accN[rg][nt] = __builtin_amdgcn_mfma_f32_16x16x32_bf16(a[rg], bN, accN[rg][nt], 0, 0, 0);
            }
        }
    }

#pragma unroll
    for (int nt = 0; nt < 4; ++nt) {
        int col = nt * 16 + l15;
        float bv = bias[col];
#pragma unroll
        for (int rg = 0; rg < 2; ++rg)
#pragma unroll
            for (int rr = 0; rr < 4; ++rr) {
                int row = rb + rg * 16 + quad * 4 + rr;
                if (row < M) {
                    x1h[(size_t)row * 64 + col] = f2b(accN[rg][nt][rr]);
                    outp[(size_t)row * 64 + col] = accS[rg][nt][rr] + bv;
                }
            }
    }
}

// ---------------- launch ----------------

extern "C" void kernel_launch(void* const* d_in, const int* in_sizes, int n_in,
                              void* d_out, int out_size, void* d_ws, size_t ws_size,
                              hipStream_t stream) {
    const float* features = (const float*)d_in[0];
    const int* esrc = (const int*)d_in[1];
    const int* edst = (const int*)d_in[2];
    const float* W1s = (const float*)d_in[3];
    const float* W1n = (const float*)d_in[4];
    const float* b1  = (const float*)d_in[5];
    const float* W2s = (const float*)d_in[6];
    const float* W2n = (const float*)d_in[7];
    const float* b2  = (const float*)d_in[8];
    float* out = (float*)d_out;

    char* ws = (char*)d_ws;
    size_t off = 0;
    auto alloc = [&](size_t bytes) {
        void* p = ws + off;
        off += (bytes + 255) & ~(size_t)255;
        return p;
    };
    int* deg        = (int*)alloc((size_t)NODES * 4);
    int* row_ptr    = (int*)alloc((size_t)(NODES + 1) * 4);
    int* cursor     = (int*)alloc((size_t)NODES * 4);
    int* part       = (int*)alloc(128 * 4);
    int* src_sorted = (int*)alloc((size_t)EDGES * 4);
    unsigned short* featb = (unsigned short*)alloc((size_t)NODES * 128 * 2);
    unsigned short* agg1  = (unsigned short*)alloc((size_t)NODES * 128 * 2);
    unsigned short* x1    = (unsigned short*)alloc((size_t)NODES * 128 * 2);
    unsigned short* x1h   = (unsigned short*)alloc((size_t)NODES * 64 * 2);
    unsigned short* Wt1s  = (unsigned short*)alloc(16384 * 2);
    unsigned short* Wt1n  = (unsigned short*)alloc(16384 * 2);
    unsigned short* Wt2s  = (unsigned short*)alloc(8192 * 2);
    unsigned short* Wt2n  = (unsigned short*)alloc(8192 * 2);

    // conversions (independent of CSR build)
    f2b_kernel<<<(NODES * 128 / 4 + 255) / 256, 256, 0, stream>>>(features, featb, NODES * 128 / 4);
    wconv_kernel<<<64, 256, 0, stream>>>(W1s, W1n, W2s, W2n, Wt1s, Wt1n, Wt2s, Wt2n);

    // CSR build
    hipMemsetAsync(deg, 0, (size_t)NODES * 4, stream);
    hist_kernel<<<(EDGES + 255) / 256, 256, 0, stream>>>(edst, deg);
    int nblk = (NODES + 1023) / 1024;  // 98
    scanA_kernel<<<nblk, 1024, 0, stream>>>(deg, row_ptr, part);
    scanB_kernel<<<1, 128, 0, stream>>>(part, row_ptr, nblk);
    scanC_kernel<<<nblk, 1024, 0, stream>>>(deg, row_ptr, cursor, part);
    scatter_kernel<<<(EDGES + 255) / 256, 256, 0, stream>>>(esrc, edst, cursor, src_sorted);

    // layer 1
    agg128_bf16<<<(NODES * 64 + 255) / 256, 256, 0, stream>>>(featb, row_ptr, src_sorted, agg1);
    gemm1_mfma<<<(NODES + 127) / 128, 256, 0, stream>>>(featb, agg1, Wt1s, Wt1n, b1, x1, NODES);

    // layer 2: x1h = x1@W2n; out = x1@W2s + b2; then out += mean-neigh(x1h)
    gemm2_mfma<<<(NODES + 127) / 128, 256, 0, stream>>>(x1, Wt2s, Wt2n, b2, x1h, out, NODES);
    agg64_add<<<(NODES * 32 + 255) / 256, 256, 0, stream>>>(x1h, row_ptr, src_sorted, out);
}

// Round 3
// 459.761 us; speedup vs baseline: 1.5280x; 1.1783x over previous
//
#include <hip/hip_runtime.h>

#define NODES 100000
#define EDGES 1600000
#define BSH 8
#define NBUCK ((NODES + 255) >> BSH)   // 391
#define CHUNK 4096
#define LMAX 8192
// IN_F = HID_F = 128, OUT_F = 64

using bf16x8 = __attribute__((ext_vector_type(8))) short;
using f32x4  = __attribute__((ext_vector_type(4))) float;

__device__ __forceinline__ unsigned short f2b(float f) {
    unsigned u = __builtin_bit_cast(unsigned, f);
    unsigned r = (u + 0x7FFFu + ((u >> 16) & 1u)) >> 16;
    return (unsigned short)r;
}
__device__ __forceinline__ float blo(unsigned u) {
    return __builtin_bit_cast(float, u << 16);
}
__device__ __forceinline__ float bhi(unsigned u) {
    return __builtin_bit_cast(float, u & 0xFFFF0000u);
}

// ---------------- CSR build ----------------

__global__ void hist_kernel(const int* __restrict__ dst, int* __restrict__ deg) {
    int e = blockIdx.x * 256 + threadIdx.x;
    if (e < EDGES) atomicAdd(&deg[dst[e]], 1);
}

__global__ void scanA_kernel(const int* __restrict__ deg, int* __restrict__ incl,
                             int* __restrict__ part) {
    __shared__ int sh[1024];
    int i = blockIdx.x * 1024 + threadIdx.x;
    int v = (i < NODES) ? deg[i] : 0;
    sh[threadIdx.x] = v;
    __syncthreads();
    for (int off = 1; off < 1024; off <<= 1) {
        int x = (threadIdx.x >= off) ? sh[threadIdx.x - off] : 0;
        __syncthreads();
        sh[threadIdx.x] += x;
        __syncthreads();
    }
    if (i < NODES) incl[i] = sh[threadIdx.x];
    if (threadIdx.x == 1023) part[blockIdx.x] = sh[1023];
}

__global__ void scanB_kernel(int* __restrict__ part, int* __restrict__ row_ptr, int nblk) {
    __shared__ int sh[128];
    int t = threadIdx.x;
    int v = (t < nblk) ? part[t] : 0;
    sh[t] = v;
    __syncthreads();
    for (int off = 1; off < 128; off <<= 1) {
        int x = (t >= off) ? sh[t - off] : 0;
        __syncthreads();
        sh[t] += x;
        __syncthreads();
    }
    if (t < nblk) part[t] = sh[t] - v;  // exclusive block offsets
    if (t == 127) row_ptr[NODES] = sh[127];
}

__global__ void scanC_kernel(const int* __restrict__ deg, int* __restrict__ row_ptr,
                             int* __restrict__ gcursor, const int* __restrict__ part) {
    int i = blockIdx.x * 1024 + threadIdx.x;
    if (i < NODES) {
        int excl = row_ptr[i] - deg[i] + part[blockIdx.x];
        row_ptr[i] = excl;
        if ((i & 255) == 0) gcursor[i >> BSH] = excl;
    }
}

// Bin edges by coarse bucket (dst>>8) via LDS counting sort; write
// bucket-contiguous runs into pairs[] whose bucket regions == CSR regions.
__global__ __launch_bounds__(256) void binscat_kernel(
    const int* __restrict__ src, const int* __restrict__ dst,
    int* __restrict__ gcursor, uint2* __restrict__ pairs) {
    __shared__ int cnt[512];
    __shared__ int scn[512];
    __shared__ int gbs[512];
    __shared__ int cur[512];
    __shared__ uint2 stage[CHUNK];
    int t = threadIdx.x;
    int base = blockIdx.x * CHUNK;
    int n = EDGES - base;
    if (n > CHUNK) n = CHUNK;

    cnt[t] = 0; cnt[t + 256] = 0;
    __syncthreads();

    uint2 my[16];
#pragma unroll
    for (int i = 0; i < 16; ++i) {
        int idx = t + i * 256;
        if (idx < n) {
            int d = dst[base + idx];
            int s = src[base + idx];
            my[i] = make_uint2((unsigned)d, (unsigned)s);
            atomicAdd(&cnt[d >> BSH], 1);
        } else {
            my[i] = make_uint2(0xFFFFFFFFu, 0);
        }
    }
    __syncthreads();
    // inclusive scan cnt -> scn
    scn[t] = cnt[t]; scn[t + 256] = cnt[t + 256];
    __syncthreads();
    for (int off = 1; off < 512; off <<= 1) {
        int a0 = (t >= off) ? scn[t - off] : 0;
        int a1 = (t + 256 >= off) ? scn[t + 256 - off] : 0;
        __syncthreads();
        scn[t] += a0; scn[t + 256] += a1;
        __syncthreads();
    }
    cur[t] = scn[t] - cnt[t];
    cur[t + 256] = scn[t + 256] - cnt[t + 256];
    __syncthreads();
    // place into stage (LDS scatter) + reserve global space per bucket
#pragma unroll
    for (int i = 0; i < 16; ++i) {
        if (my[i].x != 0xFFFFFFFFu) {
            int b = (int)(my[i].x >> BSH);
            int p = atomicAdd(&cur[b], 1);
            stage[p] = my[i];
        }
    }
    for (int b2 = t; b2 < 512; b2 += 256) {
        int c = cnt[b2];
        gbs[b2] = (c > 0 && b2 < NBUCK) ? atomicAdd(&gcursor[b2], c) : 0;
    }
    __syncthreads();
    // coalesced copy-out of bucket-contiguous runs
    for (int idx = t; idx < n; idx += 256) {
        uint2 p = stage[idx];
        int b = (int)(p.x >> BSH);
        int excl = scn[b] - cnt[b];
        pairs[gbs[b] + idx - excl] = p;
    }
}

// One block per bucket: scatter bucket's srcs to CSR order inside LDS,
// then one contiguous coalesced copy to src_sorted.
__global__ __launch_bounds__(256) void localsort_kernel(
    const uint2* __restrict__ pairs, const int* __restrict__ row_ptr,
    int* __restrict__ src_sorted) {
    __shared__ int cur[256];
    __shared__ int stage[LMAX];
    int b = blockIdx.x;
    int t = threadIdx.x;
    int node0 = b << BSH;
    int node1 = node0 + 256;
    if (node1 > NODES) node1 = NODES;
    int rbeg = row_ptr[node0];
    int rend = row_ptr[node1];
    int cnt = rend - rbeg;
    int node = node0 + t;
    cur[t] = (node < node1) ? (row_ptr[node] - rbeg) : 0;
    __syncthreads();
    if (cnt <= LMAX) {
        for (int e = rbeg + t; e < rend; e += 256) {
            uint2 p = pairs[e];
            int pos = atomicAdd(&cur[(int)(p.x & 255u)], 1);
            stage[pos] = (int)p.y;
        }
        __syncthreads();
        for (int i = t; i < cnt; i += 256) src_sorted[rbeg + i] = stage[i];
    } else {  // overflow fallback (not expected for this graph)
        for (int e = rbeg + t; e < rend; e += 256) {
            uint2 p = pairs[e];
            int pos = atomicAdd(&cur[(int)(p.x & 255u)], 1);
            src_sorted[rbeg + pos] = (int)p.y;
        }
    }
}

// ---------------- conversions ----------------

__global__ void f2b_kernel(const float* __restrict__ in, unsigned short* __restrict__ out, int n4) {
    int i = blockIdx.x * 256 + threadIdx.x;
    if (i < n4) {
        float4 v = reinterpret_cast<const float4*>(in)[i];
        uint2 o;
        o.x = (unsigned)f2b(v.x) | ((unsigned)f2b(v.y) << 16);
        o.y = (unsigned)f2b(v.z) | ((unsigned)f2b(v.w) << 16);
        reinterpret_cast<uint2*>(out)[i] = o;
    }
}

// transpose+convert weights: W[k][n] f32 -> Wt[n][k] bf16 (k stride 128)
__global__ void wconv_kernel(const float* __restrict__ W1s, const float* __restrict__ W1n,
                             const float* __restrict__ W2s, const float* __restrict__ W2n,
                             unsigned short* __restrict__ Wt1s, unsigned short* __restrict__ Wt1n,
                             unsigned short* __restrict__ Wt2s, unsigned short* __restrict__ Wt2n) {
    int t = blockIdx.x * 256 + threadIdx.x;
    if (t < 16384) {
        int k = t >> 7, n = t & 127;
        Wt1s[n * 128 + k] = f2b(W1s[t]);
        Wt1n[n * 128 + k] = f2b(W1n[t]);
    }
    if (t < 8192) {
        int k = t >> 6, n = t & 63;
        Wt2s[n * 128 + k] = f2b(W2s[t]);
        Wt2n[n * 128 + k] = f2b(W2n[t]);
    }
}

// ---------------- Mean aggregation (gather via CSR), bf16 ----------------

__global__ void agg128_bf16(const unsigned short* __restrict__ xb, const int* __restrict__ row_ptr,
                            const int* __restrict__ srcs, unsigned short* __restrict__ out) {
    int w = (blockIdx.x * blockDim.x + threadIdx.x) >> 6;
    int lane = threadIdx.x & 63;
    if (w >= NODES) return;
    int beg = row_ptr[w], end = row_ptr[w + 1];
    float s0a = 0.f, s0b = 0.f, s1a = 0.f, s1b = 0.f;
    int e = beg;
    for (; e + 2 <= end; e += 2) {
        int n0 = srcs[e], n1 = srcs[e + 1];
        unsigned u0 = *reinterpret_cast<const unsigned*>(xb + (size_t)n0 * 128 + lane * 2);
        unsigned u1 = *reinterpret_cast<const unsigned*>(xb + (size_t)n1 * 128 + lane * 2);
        s0a += blo(u0); s0b += bhi(u0);
        s1a += blo(u1); s1b += bhi(u1);
    }
    if (e < end) {
        unsigned u0 = *reinterpret_cast<const unsigned*>(xb + (size_t)srcs[e] * 128 + lane * 2);
        s0a += blo(u0); s0b += bhi(u0);
    }
    float inv = 1.0f / fmaxf((float)(end - beg), 1.0f);
    unsigned o = (unsigned)f2b((s0a + s1a) * inv) | ((unsigned)f2b((s0b + s1b) * inv) << 16);
    *reinterpret_cast<unsigned*>(out + (size_t)w * 128 + lane * 2) = o;
}

__global__ void agg64_add(const unsigned short* __restrict__ xh, const int* __restrict__ row_ptr,
                          const int* __restrict__ srcs, float* __restrict__ out) {
    int t = blockIdx.x * blockDim.x + threadIdx.x;
    int node = t >> 5;
    int l = t & 31;
    if (node >= NODES) return;
    int beg = row_ptr[node], end = row_ptr[node + 1];
    float s0a = 0.f, s0b = 0.f, s1a = 0.f, s1b = 0.f;
    int e = beg;
    for (; e + 2 <= end; e += 2) {
        int n0 = srcs[e], n1 = srcs[e + 1];
        unsigned u0 = *reinterpret_cast<const unsigned*>(xh + (size_t)n0 * 64 + l * 2);
        unsigned u1 = *reinterpret_cast<const unsigned*>(xh + (size_t)n1 * 64 + l * 2);
        s0a += blo(u0); s0b += bhi(u0);
        s1a += blo(u1); s1b += bhi(u1);
    }
    if (e < end) {
        unsigned u0 = *reinterpret_cast<const unsigned*>(xh + (size_t)srcs[e] * 64 + l * 2);
        s0a += blo(u0); s0b += bhi(u0);
    }
    float inv = 1.0f / fmaxf((float)(end - beg), 1.0f);
    float2 p = *reinterpret_cast<float2*>(out + (size_t)node * 64 + l * 2);
    p.x += (s0a + s1a) * inv;
    p.y += (s0b + s1b) * inv;
    *reinterpret_cast<float2*>(out + (size_t)node * 64 + l * 2) = p;
}

// ---------------- MFMA GEMMs (bf16 in, K=128) ----------------

__global__ __launch_bounds__(256) void gemm1_mfma(
    const unsigned short* __restrict__ feat, const unsigned short* __restrict__ agg,
    const unsigned short* __restrict__ Wt0, const unsigned short* __restrict__ Wt1,
    const float* __restrict__ bias, unsigned short* __restrict__ x1, int M) {
    int wid = threadIdx.x >> 6, lane = threadIdx.x & 63;
    int l15 = lane & 15, quad = lane >> 4;
    int rb = blockIdx.x * 128 + wid * 32;

    f32x4 acc[2][8];
#pragma unroll
    for (int rg = 0; rg < 2; ++rg)
#pragma unroll
        for (int nt = 0; nt < 8; ++nt) acc[rg][nt] = {0.f, 0.f, 0.f, 0.f};

#pragma unroll
    for (int k0 = 0; k0 < 128; k0 += 32) {
        bf16x8 a0[2], a1[2];
#pragma unroll
        for (int rg = 0; rg < 2; ++rg) {
            int r = rb + rg * 16 + l15;
            if (r >= M) r = M - 1;
            a0[rg] = *reinterpret_cast<const bf16x8*>(feat + (size_t)r * 128 + quad * 8 + k0);
            a1[rg] = *reinterpret_cast<const bf16x8*>(agg + (size_t)r * 128 + quad * 8 + k0);
        }
#pragma unroll
        for (int nt = 0; nt < 8; ++nt) {
            bf16x8 b0 = *reinterpret_cast<const bf16x8*>(Wt0 + (size_t)(nt * 16 + l15) * 128 + quad * 8 + k0);
            bf16x8 b1 = *reinterpret_cast<const bf16x8*>(Wt1 + (size_t)(nt * 16 + l15) * 128 + quad * 8 + k0);
#pragma unroll
            for (int rg = 0; rg < 2; ++rg) {
                acc[rg][nt] = __builtin_amdgcn_mfma_f32_16x16x32_bf16(a0[rg], b0, acc[rg][nt], 0, 0, 0);
                acc[rg][nt] = __builtin_amdgcn_mfma_f32_16x16x32_bf16(a1[rg], b1, acc[rg][nt], 0, 0, 0);
            }
        }
    }

#pragma unroll
    for (int nt = 0; nt < 8; ++nt) {
        int col = nt * 16 + l15;
        float bv = bias[col];
#pragma unroll
        for (int rg = 0; rg < 2; ++rg)
#pragma unroll
            for (int rr = 0; rr < 4; ++rr) {
                int row = rb + rg * 16 + quad * 4 + rr;
                if (row < M) {
                    float v = fmaxf(acc[rg][nt][rr] + bv, 0.f);
                    x1[(size_t)row * 128 + col] = f2b(v);
                }
            }
    }
}

__global__ __launch_bounds__(256) void gemm2_mfma(
    const unsigned short* __restrict__ x1,
    const unsigned short* __restrict__ WtS, const unsigned short* __restrict__ WtN,
    const float* __restrict__ bias, unsigned short* __restrict__ x1h,
    float* __restrict__ outp, int M) {
    int wid = threadIdx.x >> 6, lane = threadIdx.x & 63;
    int l15 = lane & 15, quad = lane >> 4;
    int rb = blockIdx.x * 128 + wid * 32;

    f32x4 accS[2][4], accN[2][4];
#pragma unroll
    for (int rg = 0; rg < 2; ++rg)
#pragma unroll
        for (int nt = 0; nt < 4; ++nt) {
            accS[rg][nt] = {0.f, 0.f, 0.f, 0.f};
            accN[rg][nt] = {0.f, 0.f, 0.f, 0.f};
        }

#pragma unroll
    for (int k0 = 0; k0 < 128; k0 += 32) {
        bf16x8 a[2];
#pragma unroll
        for (int rg = 0; rg < 2; ++rg) {
            int r = rb + rg * 16 + l15;
            if (r >= M) r = M - 1;
            a[rg] = *reinterpret_cast<const bf16x8*>(x1 + (size_t)r * 128 + quad * 8 + k0);
        }
#pragma unroll
        for (int nt = 0; nt < 4; ++nt) {
            bf16x8 bS = *reinterpret_cast<const bf16x8*>(WtS + (size_t)(nt * 16 + l15) * 128 + quad * 8 + k0);
            bf16x8 bN = *reinterpret_cast<const bf16x8*>(WtN + (size_t)(nt * 16 + l15) * 128 + quad * 8 + k0);
#pragma unroll
            for (int rg = 0; rg < 2; ++rg) {
                accS[rg][nt] = __builtin_amdgcn_mfma_f32_16x16x32_bf16(a[rg], bS, accS[rg][nt], 0, 0, 0);
                accN[rg][nt] = __builtin_amdgcn_mfma_f32_16x16x32_bf16(a[rg], bN, accN[rg][nt], 0, 0, 0);
            }
        }
    }

#pragma unroll
    for (int nt = 0; nt < 4; ++nt) {
        int col = nt * 16 + l15;
        float bv = bias[col];
#pragma unroll
        for (int rg = 0; rg < 2; ++rg)
#pragma unroll
            for (int rr = 0; rr < 4; ++rr) {
                int row = rb + rg * 16 + quad * 4 + rr;
                if (row < M) {
                    x1h[(size_t)row * 64 + col] = f2b(accN[rg][nt][rr]);
                    outp[(size_t)row * 64 + col] = accS[rg][nt][rr] + bv;
                }
            }
    }
}

// ---------------- launch ----------------

extern "C" void kernel_launch(void* const* d_in, const int* in_sizes, int n_in,
                              void* d_out, int out_size, void* d_ws, size_t ws_size,
                              hipStream_t stream) {
    const float* features = (const float*)d_in[0];
    const int* esrc = (const int*)d_in[1];
    const int* edst = (const int*)d_in[2];
    const float* W1s = (const float*)d_in[3];
    const float* W1n = (const float*)d_in[4];
    const float* b1  = (const float*)d_in[5];
    const float* W2s = (const float*)d_in[6];
    const float* W2n = (const float*)d_in[7];
    const float* b2  = (const float*)d_in[8];
    float* out = (float*)d_out;

    char* ws = (char*)d_ws;
    size_t off = 0;
    auto alloc = [&](size_t bytes) {
        void* p = ws + off;
        off += (bytes + 255) & ~(size_t)255;
        return p;
    };
    int* deg        = (int*)alloc((size_t)NODES * 4);
    int* row_ptr    = (int*)alloc((size_t)(NODES + 1) * 4);
    int* gcursor    = (int*)alloc(512 * 4);
    int* part       = (int*)alloc(128 * 4);
    int* src_sorted = (int*)alloc((size_t)EDGES * 4);
    uint2* pairs    = (uint2*)alloc((size_t)EDGES * 8);
    unsigned short* featb = (unsigned short*)alloc((size_t)NODES * 128 * 2);
    unsigned short* agg1  = (unsigned short*)alloc((size_t)NODES * 128 * 2);
    unsigned short* x1    = (unsigned short*)alloc((size_t)NODES * 128 * 2);
    unsigned short* x1h   = (unsigned short*)alloc((size_t)NODES * 64 * 2);
    unsigned short* Wt1s  = (unsigned short*)alloc(16384 * 2);
    unsigned short* Wt1n  = (unsigned short*)alloc(16384 * 2);
    unsigned short* Wt2s  = (unsigned short*)alloc(8192 * 2);
    unsigned short* Wt2n  = (unsigned short*)alloc(8192 * 2);

    // conversions (independent of CSR build)
    f2b_kernel<<<(NODES * 128 / 4 + 255) / 256, 256, 0, stream>>>(features, featb, NODES * 128 / 4);
    wconv_kernel<<<64, 256, 0, stream>>>(W1s, W1n, W2s, W2n, Wt1s, Wt1n, Wt2s, Wt2n);

    // CSR build
    hipMemsetAsync(deg, 0, (size_t)NODES * 4, stream);
    hist_kernel<<<(EDGES + 255) / 256, 256, 0, stream>>>(edst, deg);
    int nblk = (NODES + 1023) / 1024;  // 98
    scanA_kernel<<<nblk, 1024, 0, stream>>>(deg, row_ptr, part);
    scanB_kernel<<<1, 128, 0, stream>>>(part, row_ptr, nblk);
    scanC_kernel<<<nblk, 1024, 0, stream>>>(deg, row_ptr, gcursor, part);
    binscat_kernel<<<(EDGES + CHUNK - 1) / CHUNK, 256, 0, stream>>>(esrc, edst, gcursor, pairs);
    localsort_kernel<<<NBUCK, 256, 0, stream>>>(pairs, row_ptr, src_sorted);

    // layer 1
    agg128_bf16<<<(NODES * 64 + 255) / 256, 256, 0, stream>>>(featb, row_ptr, src_sorted, agg1);
    gemm1_mfma<<<(NODES + 127) / 128, 256, 0, stream>>>(featb, agg1, Wt1s, Wt1n, b1, x1, NODES);

    // layer 2: x1h = x1@W2n; out = x1@W2s + b2; then out += mean-neigh(x1h)
    gemm2_mfma<<<(NODES + 127) / 128, 256, 0, stream>>>(x1, Wt2s, Wt2n, b2, x1h, out, NODES);
    agg64_add<<<(NODES * 32 + 255) / 256, 256, 0, stream>>>(x1h, row_ptr, src_sorted, out);
}

// Round 5
// 408.665 us; speedup vs baseline: 1.7191x; 1.1250x over previous
//
#include <hip/hip_runtime.h>

#define NODES 100000
#define EDGES 1600000
#define BSH 8
#define NBUCK ((NODES + 255) >> BSH)   // 391
#define CHUNK 4096
#define LMAX 8192
// IN_F = HID_F = 128, OUT_F = 64

using bf16x8 = __attribute__((ext_vector_type(8))) short;
using f32x4  = __attribute__((ext_vector_type(4))) float;

__device__ __forceinline__ unsigned short f2b(float f) {
    unsigned u = __builtin_bit_cast(unsigned, f);
    unsigned r = (u + 0x7FFFu + ((u >> 16) & 1u)) >> 16;
    return (unsigned short)r;
}
__device__ __forceinline__ float blo(unsigned u) {
    return __builtin_bit_cast(float, u << 16);
}
__device__ __forceinline__ float bhi(unsigned u) {
    return __builtin_bit_cast(float, u & 0xFFFF0000u);
}

// ---------------- CSR build ----------------

__global__ void hist_kernel(const int* __restrict__ dst, int* __restrict__ deg) {
    int e = blockIdx.x * 256 + threadIdx.x;
    if (e < EDGES) atomicAdd(&deg[dst[e]], 1);
}

__global__ void scanA_kernel(const int* __restrict__ deg, int* __restrict__ incl,
                             int* __restrict__ part) {
    __shared__ int sh[1024];
    int i = blockIdx.x * 1024 + threadIdx.x;
    int v = (i < NODES) ? deg[i] : 0;
    sh[threadIdx.x] = v;
    __syncthreads();
    for (int off = 1; off < 1024; off <<= 1) {
        int x = (threadIdx.x >= off) ? sh[threadIdx.x - off] : 0;
        __syncthreads();
        sh[threadIdx.x] += x;
        __syncthreads();
    }
    if (i < NODES) incl[i] = sh[threadIdx.x];
    if (threadIdx.x == 1023) part[blockIdx.x] = sh[1023];
}

__global__ void scanB_kernel(int* __restrict__ part, int* __restrict__ row_ptr, int nblk) {
    __shared__ int sh[128];
    int t = threadIdx.x;
    int v = (t < nblk) ? part[t] : 0;
    sh[t] = v;
    __syncthreads();
    for (int off = 1; off < 128; off <<= 1) {
        int x = (t >= off) ? sh[t - off] : 0;
        __syncthreads();
        sh[t] += x;
        __syncthreads();
    }
    if (t < nblk) part[t] = sh[t] - v;  // exclusive block offsets
    if (t == 127) row_ptr[NODES] = sh[127];
}

__global__ void scanC_kernel(const int* __restrict__ deg, int* __restrict__ row_ptr,
                             int* __restrict__ gcursor, const int* __restrict__ part) {
    int i = blockIdx.x * 1024 + threadIdx.x;
    if (i < NODES) {
        int excl = row_ptr[i] - deg[i] + part[blockIdx.x];
        row_ptr[i] = excl;
        if ((i & 255) == 0) gcursor[i >> BSH] = excl;
    }
}

// Bin edges by coarse bucket (dst>>8) via LDS counting sort; write
// bucket-contiguous runs into pairs[] whose bucket regions == CSR regions.
__global__ __launch_bounds__(256) void binscat_kernel(
    const int* __restrict__ src, const int* __restrict__ dst,
    int* __restrict__ gcursor, uint2* __restrict__ pairs) {
    __shared__ int cnt[512];
    __shared__ int scn[512];
    __shared__ int gbs[512];
    __shared__ int cur[512];
    __shared__ uint2 stage[CHUNK];
    int t = threadIdx.x;
    int base = blockIdx.x * CHUNK;
    int n = EDGES - base;
    if (n > CHUNK) n = CHUNK;

    cnt[t] = 0; cnt[t + 256] = 0;
    __syncthreads();

    uint2 my[16];
#pragma unroll
    for (int i = 0; i < 16; ++i) {
        int idx = t + i * 256;
        if (idx < n) {
            int d = dst[base + idx];
            int s = src[base + idx];
            my[i] = make_uint2((unsigned)d, (unsigned)s);
            atomicAdd(&cnt[d >> BSH], 1);
        } else {
            my[i] = make_uint2(0xFFFFFFFFu, 0);
        }
    }
    __syncthreads();
    // inclusive scan cnt -> scn
    scn[t] = cnt[t]; scn[t + 256] = cnt[t + 256];
    __syncthreads();
    for (int off = 1; off < 512; off <<= 1) {
        int a0 = (t >= off) ? scn[t - off] : 0;
        int a1 = (t + 256 >= off) ? scn[t + 256 - off] : 0;
        __syncthreads();
        scn[t] += a0; scn[t + 256] += a1;
        __syncthreads();
    }
    cur[t] = scn[t] - cnt[t];
    cur[t + 256] = scn[t + 256] - cnt[t + 256];
    __syncthreads();
    // place into stage (LDS scatter) + reserve global space per bucket
#pragma unroll
    for (int i = 0; i < 16; ++i) {
        if (my[i].x != 0xFFFFFFFFu) {
            int b = (int)(my[i].x >> BSH);
            int p = atomicAdd(&cur[b], 1);
            stage[p] = my[i];
        }
    }
    for (int b2 = t; b2 < 512; b2 += 256) {
        int c = cnt[b2];
        gbs[b2] = (c > 0 && b2 < NBUCK) ? atomicAdd(&gcursor[b2], c) : 0;
    }
    __syncthreads();
    // coalesced copy-out of bucket-contiguous runs
    for (int idx = t; idx < n; idx += 256) {
        uint2 p = stage[idx];
        int b = (int)(p.x >> BSH);
        int excl = scn[b] - cnt[b];
        pairs[gbs[b] + idx - excl] = p;
    }
}

// One block per bucket: scatter bucket's srcs to CSR order inside LDS,
// then one contiguous coalesced copy to src_sorted.
__global__ __launch_bounds__(256) void localsort_kernel(
    const uint2* __restrict__ pairs, const int* __restrict__ row_ptr,
    int* __restrict__ src_sorted) {
    __shared__ int cur[256];
    __shared__ int stage[LMAX];
    int b = blockIdx.x;
    int t = threadIdx.x;
    int node0 = b << BSH;
    int node1 = node0 + 256;
    if (node1 > NODES) node1 = NODES;
    int rbeg = row_ptr[node0];
    int rend = row_ptr[node1];
    int cnt = rend - rbeg;
    int node = node0 + t;
    cur[t] = (node < node1) ? (row_ptr[node] - rbeg) : 0;
    __syncthreads();
    if (cnt <= LMAX) {
        for (int e = rbeg + t; e < rend; e += 256) {
            uint2 p = pairs[e];
            int pos = atomicAdd(&cur[(int)(p.x & 255u)], 1);
            stage[pos] = (int)p.y;
        }
        __syncthreads();
        for (int i = t; i < cnt; i += 256) src_sorted[rbeg + i] = stage[i];
    } else {  // overflow fallback (not expected for this graph)
        for (int e = rbeg + t; e < rend; e += 256) {
            uint2 p = pairs[e];
            int pos = atomicAdd(&cur[(int)(p.x & 255u)], 1);
            src_sorted[rbeg + pos] = (int)p.y;
        }
    }
}

// ---------------- conversions ----------------

__global__ void f2b_kernel(const float* __restrict__ in, unsigned short* __restrict__ out, int n4) {
    int i = blockIdx.x * 256 + threadIdx.x;
    if (i < n4) {
        float4 v = reinterpret_cast<const float4*>(in)[i];
        uint2 o;
        o.x = (unsigned)f2b(v.x) | ((unsigned)f2b(v.y) << 16);
        o.y = (unsigned)f2b(v.z) | ((unsigned)f2b(v.w) << 16);
        reinterpret_cast<uint2*>(out)[i] = o;
    }
}

// transpose+convert weights: W[k][n] f32 -> Wt[n][k] bf16 (k stride 128)
__global__ void wconv_kernel(const float* __restrict__ W1s, const float* __restrict__ W1n,
                             const float* __restrict__ W2s, const float* __restrict__ W2n,
                             unsigned short* __restrict__ Wt1s, unsigned short* __restrict__ Wt1n,
                             unsigned short* __restrict__ Wt2s, unsigned short* __restrict__ Wt2n) {
    int t = blockIdx.x * 256 + threadIdx.x;
    if (t < 16384) {
        int k = t >> 7, n = t & 127;
        Wt1s[n * 128 + k] = f2b(W1s[t]);
        Wt1n[n * 128 + k] = f2b(W1n[t]);
    }
    if (t < 8192) {
        int k = t >> 6, n = t & 63;
        Wt2s[n * 128 + k] = f2b(W2s[t]);
        Wt2n[n * 128 + k] = f2b(W2n[t]);
    }
}

// ---------------- Mean aggregation (gather via CSR), bf16, wide ----------------
// One wave per node. 16 lanes per edge-row (16B/lane), 4 edge groups, unroll 2:
// 8 row-gathers (2KB) in flight. Cross-group reduce via shfl_xor.

__global__ __launch_bounds__(256) void agg128_bf16(
    const unsigned short* __restrict__ xb, const int* __restrict__ row_ptr,
    const int* __restrict__ srcs, unsigned short* __restrict__ out) {
    int w = (blockIdx.x * 256 + threadIdx.x) >> 6;
    int lane = threadIdx.x & 63;
    if (w >= NODES) return;
    int g = lane >> 4;   // edge group 0..3
    int sl = lane & 15;  // feature sublane: 8 bf16 = 16B
    int beg = row_ptr[w], end = row_ptr[w + 1];

    float a0[8], a1[8];
#pragma unroll
    for (int i = 0; i < 8; ++i) { a0[i] = 0.f; a1[i] = 0.f; }

    const unsigned short* xs = xb + sl * 8;
    int e = beg + g;
    for (; e + 4 < end; e += 8) {
        int s0 = srcs[e];
        int s1 = srcs[e + 4];
        uint4 v0 = *reinterpret_cast<const uint4*>(xs + (size_t)s0 * 128);
        uint4 v1 = *reinterpret_cast<const uint4*>(xs + (size_t)s1 * 128);
        a0[0] += blo(v0.x); a0[1] += bhi(v0.x);
        a0[2] += blo(v0.y); a0[3] += bhi(v0.y);
        a0[4] += blo(v0.z); a0[5] += bhi(v0.z);
        a0[6] += blo(v0.w); a0[7] += bhi(v0.w);
        a1[0] += blo(v1.x); a1[1] += bhi(v1.x);
        a1[2] += blo(v1.y); a1[3] += bhi(v1.y);
        a1[4] += blo(v1.z); a1[5] += bhi(v1.z);
        a1[6] += blo(v1.w); a1[7] += bhi(v1.w);
    }
    if (e < end) {
        int s0 = srcs[e];
        uint4 v0 = *reinterpret_cast<const uint4*>(xs + (size_t)s0 * 128);
        a0[0] += blo(v0.x); a0[1] += bhi(v0.x);
        a0[2] += blo(v0.y); a0[3] += bhi(v0.y);
        a0[4] += blo(v0.z); a0[5] += bhi(v0.z);
        a0[6] += blo(v0.w); a0[7] += bhi(v0.w);
    }
#pragma unroll
    for (int i = 0; i < 8; ++i) {
        float s = a0[i] + a1[i];
        s += __shfl_xor(s, 16, 64);
        s += __shfl_xor(s, 32, 64);
        a0[i] = s;
    }
    if (g == 0) {
        float inv = 1.0f / fmaxf((float)(end - beg), 1.0f);
        uint4 o;
        o.x = (unsigned)f2b(a0[0] * inv) | ((unsigned)f2b(a0[1] * inv) << 16);
        o.y = (unsigned)f2b(a0[2] * inv) | ((unsigned)f2b(a0[3] * inv) << 16);
        o.z = (unsigned)f2b(a0[4] * inv) | ((unsigned)f2b(a0[5] * inv) << 16);
        o.w = (unsigned)f2b(a0[6] * inv) | ((unsigned)f2b(a0[7] * inv) << 16);
        *reinterpret_cast<uint4*>(out + (size_t)w * 128 + sl * 8) = o;
    }
}

// One wave per node, 64 bf16 features (128B/row): 8 lanes per edge-row,
// 8 edge groups, unroll 2 -> 16 rows in flight. Adds mean into f32 out.
__global__ __launch_bounds__(256) void agg64_add(
    const unsigned short* __restrict__ xh, const int* __restrict__ row_ptr,
    const int* __restrict__ srcs, float* __restrict__ out) {
    int w = (blockIdx.x * 256 + threadIdx.x) >> 6;
    int lane = threadIdx.x & 63;
    if (w >= NODES) return;
    int g = lane >> 3;  // edge group 0..7
    int sl = lane & 7;  // feature sublane: 8 bf16 = 16B
    int beg = row_ptr[w], end = row_ptr[w + 1];

    float a0[8], a1[8];
#pragma unroll
    for (int i = 0; i < 8; ++i) { a0[i] = 0.f; a1[i] = 0.f; }

    const unsigned short* xs = xh + sl * 8;
    int e = beg + g;
    for (; e + 8 < end; e += 16) {
        int s0 = srcs[e];
        int s1 = srcs[e + 8];
        uint4 v0 = *reinterpret_cast<const uint4*>(xs + (size_t)s0 * 64);
        uint4 v1 = *reinterpret_cast<const uint4*>(xs + (size_t)s1 * 64);
        a0[0] += blo(v0.x); a0[1] += bhi(v0.x);
        a0[2] += blo(v0.y); a0[3] += bhi(v0.y);
        a0[4] += blo(v0.z); a0[5] += bhi(v0.z);
        a0[6] += blo(v0.w); a0[7] += bhi(v0.w);
        a1[0] += blo(v1.x); a1[1] += bhi(v1.x);
        a1[2] += blo(v1.y); a1[3] += bhi(v1.y);
        a1[4] += blo(v1.z); a1[5] += bhi(v1.z);
        a1[6] += blo(v1.w); a1[7] += bhi(v1.w);
    }
    if (e < end) {
        int s0 = srcs[e];
        uint4 v0 = *reinterpret_cast<const uint4*>(xs + (size_t)s0 * 64);
        a0[0] += blo(v0.x); a0[1] += bhi(v0.x);
        a0[2] += blo(v0.y); a0[3] += bhi(v0.y);
        a0[4] += blo(v0.z); a0[5] += bhi(v0.z);
        a0[6] += blo(v0.w); a0[7] += bhi(v0.w);
    }
#pragma unroll
    for (int i = 0; i < 8; ++i) {
        float s = a0[i] + a1[i];
        s += __shfl_xor(s, 8, 64);
        s += __shfl_xor(s, 16, 64);
        s += __shfl_xor(s, 32, 64);
        a0[i] = s;
    }
    if (g == 0) {
        float inv = 1.0f / fmaxf((float)(end - beg), 1.0f);
        float* op = out + (size_t)w * 64 + sl * 8;
        float4 p0 = *reinterpret_cast<float4*>(op);
        float4 p1 = *reinterpret_cast<float4*>(op + 4);
        p0.x += a0[0] * inv; p0.y += a0[1] * inv;
        p0.z += a0[2] * inv; p0.w += a0[3] * inv;
        p1.x += a0[4] * inv; p1.y += a0[5] * inv;
        p1.z += a0[6] * inv; p1.w += a0[7] * inv;
        *reinterpret_cast<float4*>(op) = p0;
        *reinterpret_cast<float4*>(op + 4) = p1;
    }
}

// ---------------- MFMA GEMMs (bf16 in, K=128) ----------------

__global__ __launch_bounds__(256) void gemm1_mfma(
    const unsigned short* __restrict__ feat, const unsigned short* __restrict__ agg,
    const unsigned short* __restrict__ Wt0, const unsigned short* __restrict__ Wt1,
    const float* __restrict__ bias, unsigned short* __restrict__ x1, int M) {
    int wid = threadIdx.x >> 6, lane = threadIdx.x & 63;
    int l15 = lane & 15, quad = lane >> 4;
    int rb = blockIdx.x * 128 + wid * 32;

    f32x4 acc[2][8];
#pragma unroll
    for (int rg = 0; rg < 2; ++rg)
#pragma unroll
        for (int nt = 0; nt < 8; ++nt) acc[rg][nt] = {0.f, 0.f, 0.f, 0.f};

#pragma unroll
    for (int k0 = 0; k0 < 128; k0 += 32) {
        bf16x8 a0[2], a1[2];
#pragma unroll
        for (int rg = 0; rg < 2; ++rg) {
            int r = rb + rg * 16 + l15;
            if (r >= M) r = M - 1;
            a0[rg] = *reinterpret_cast<const bf16x8*>(feat + (size_t)r * 128 + quad * 8 + k0);
            a1[rg] = *reinterpret_cast<const bf16x8*>(agg + (size_t)r * 128 + quad * 8 + k0);
        }
#pragma unroll
        for (int nt = 0; nt < 8; ++nt) {
            bf16x8 b0 = *reinterpret_cast<const bf16x8*>(Wt0 + (size_t)(nt * 16 + l15) * 128 + quad * 8 + k0);
            bf16x8 b1 = *reinterpret_cast<const bf16x8*>(Wt1 + (size_t)(nt * 16 + l15) * 128 + quad * 8 + k0);
#pragma unroll
            for (int rg = 0; rg < 2; ++rg) {
                acc[rg][nt] = __builtin_amdgcn_mfma_f32_16x16x32_bf16(a0[rg], b0, acc[rg][nt], 0, 0, 0);
                acc[rg][nt] = __builtin_amdgcn_mfma_f32_16x16x32_bf16(a1[rg], b1, acc[rg][nt], 0, 0, 0);
            }
        }
    }

#pragma unroll
    for (int nt = 0; nt < 8; ++nt) {
        int col = nt * 16 + l15;
        float bv = bias[col];
#pragma unroll
        for (int rg = 0; rg < 2; ++rg)
#pragma unroll
            for (int rr = 0; rr < 4; ++rr) {
                int row = rb + rg * 16 + quad * 4 + rr;
                if (row < M) {
                    float v = fmaxf(acc[rg][nt][rr] + bv, 0.f);
                    x1[(size_t)row * 128 + col] = f2b(v);
                }
            }
    }
}

__global__ __launch_bounds__(256) void gemm2_mfma(
    const unsigned short* __restrict__ x1,
    const unsigned short* __restrict__ WtS, const unsigned short* __restrict__ WtN,
    const float* __restrict__ bias, unsigned short* __restrict__ x1h,
    float* __restrict__ outp, int M) {
    int wid = threadIdx.x >> 6, lane = threadIdx.x & 63;
    int l15 = lane & 15, quad = lane >> 4;
    int rb = blockIdx.x * 128 + wid * 32;

    f32x4 accS[2][4], accN[2][4];
#pragma unroll
    for (int rg = 0; rg < 2; ++rg)
#pragma unroll
        for (int nt = 0; nt < 4; ++nt) {
            accS[rg][nt] = {0.f, 0.f, 0.f, 0.f};
            accN[rg][nt] = {0.f, 0.f, 0.f, 0.f};
        }

#pragma unroll
    for (int k0 = 0; k0 < 128; k0 += 32) {
        bf16x8 a[2];
#pragma unroll
        for (int rg = 0; rg < 2; ++rg) {
            int r = rb + rg * 16 + l15;
            if (r >= M) r = M - 1;
            a[rg] = *reinterpret_cast<const bf16x8*>(x1 + (size_t)r * 128 + quad * 8 + k0);
        }
#pragma unroll
        for (int nt = 0; nt < 4; ++nt) {
            bf16x8 bS = *reinterpret_cast<const bf16x8*>(WtS + (size_t)(nt * 16 + l15) * 128 + quad * 8 + k0);
            bf16x8 bN = *reinterpret_cast<const bf16x8*>(WtN + (size_t)(nt * 16 + l15) * 128 + quad * 8 + k0);
#pragma unroll
            for (int rg = 0; rg < 2; ++rg) {
                accS[rg][nt] = __builtin_amdgcn_mfma_f32_16x16x32_bf16(a[rg], bS, accS[rg][nt], 0, 0, 0);
                accN[rg][nt] = __builtin_amdgcn_mfma_f32_16x16x32_bf16(a[rg], bN, accN[rg][nt], 0, 0, 0);
            }
        }
    }

#pragma unroll
    for (int nt = 0; nt < 4; ++nt) {
        int col = nt * 16 + l15;
        float bv = bias[col];
#pragma unroll
        for (int rg = 0; rg < 2; ++rg)
#pragma unroll
            for (int rr = 0; rr < 4; ++rr) {
                int row = rb + rg * 16 + quad * 4 + rr;
                if (row < M) {
                    x1h[(size_t)row * 64 + col] = f2b(accN[rg][nt][rr]);
                    outp[(size_t)row * 64 + col] = accS[rg][nt][rr] + bv;
                }
            }
    }
}

// ---------------- launch ----------------

extern "C" void kernel_launch(void* const* d_in, const int* in_sizes, int n_in,
                              void* d_out, int out_size, void* d_ws, size_t ws_size,
                              hipStream_t stream) {
    const float* features = (const float*)d_in[0];
    const int* esrc = (const int*)d_in[1];
    const int* edst = (const int*)d_in[2];
    const float* W1s = (const float*)d_in[3];
    const float* W1n = (const float*)d_in[4];
    const float* b1  = (const float*)d_in[5];
    const float* W2s = (const float*)d_in[6];
    const float* W2n = (const float*)d_in[7];
    const float* b2  = (const float*)d_in[8];
    float* out = (float*)d_out;

    char* ws = (char*)d_ws;
    size_t off = 0;
    auto alloc = [&](size_t bytes) {
        void* p = ws + off;
        off += (bytes + 255) & ~(size_t)255;
        return p;
    };
    int* deg        = (int*)alloc((size_t)NODES * 4);
    int* row_ptr    = (int*)alloc((size_t)(NODES + 1) * 4);
    int* gcursor    = (int*)alloc(512 * 4);
    int* part       = (int*)alloc(128 * 4);
    int* src_sorted = (int*)alloc((size_t)EDGES * 4);
    uint2* pairs    = (uint2*)alloc((size_t)EDGES * 8);
    unsigned short* featb = (unsigned short*)alloc((size_t)NODES * 128 * 2);
    unsigned short* agg1  = (unsigned short*)alloc((size_t)NODES * 128 * 2);
    unsigned short* x1    = (unsigned short*)alloc((size_t)NODES * 128 * 2);
    unsigned short* x1h   = (unsigned short*)alloc((size_t)NODES * 64 * 2);
    unsigned short* Wt1s  = (unsigned short*)alloc(16384 * 2);
    unsigned short* Wt1n  = (unsigned short*)alloc(16384 * 2);
    unsigned short* Wt2s  = (unsigned short*)alloc(8192 * 2);
    unsigned short* Wt2n  = (unsigned short*)alloc(8192 * 2);

    // conversions (independent of CSR build)
    f2b_kernel<<<(NODES * 128 / 4 + 255) / 256, 256, 0, stream>>>(features, featb, NODES * 128 / 4);
    wconv_kernel<<<64, 256, 0, stream>>>(W1s, W1n, W2s, W2n, Wt1s, Wt1n, Wt2s, Wt2n);

    // CSR build
    hipMemsetAsync(deg, 0, (size_t)NODES * 4, stream);
    hist_kernel<<<(EDGES + 255) / 256, 256, 0, stream>>>(edst, deg);
    int nblk = (NODES + 1023) / 1024;  // 98
    scanA_kernel<<<nblk, 1024, 0, stream>>>(deg, row_ptr, part);
    scanB_kernel<<<1, 128, 0, stream>>>(part, row_ptr, nblk);
    scanC_kernel<<<nblk, 1024, 0, stream>>>(deg, row_ptr, gcursor, part);
    binscat_kernel<<<(EDGES + CHUNK - 1) / CHUNK, 256, 0, stream>>>(esrc, edst, gcursor, pairs);
    localsort_kernel<<<NBUCK, 256, 0, stream>>>(pairs, row_ptr, src_sorted);

    // layer 1
    agg128_bf16<<<(NODES * 64 + 255) / 256, 256, 0, stream>>>(featb, row_ptr, src_sorted, agg1);
    gemm1_mfma<<<(NODES + 127) / 128, 256, 0, stream>>>(featb, agg1, Wt1s, Wt1n, b1, x1, NODES);

    // layer 2: x1h = x1@W2n; out = x1@W2s + b2; then out += mean-neigh(x1h)
    gemm2_mfma<<<(NODES + 127) / 128, 256, 0, stream>>>(x1, Wt2s, Wt2n, b2, x1h, out, NODES);
    agg64_add<<<(NODES * 64 + 255) / 256, 256, 0, stream>>>(x1h, row_ptr, src_sorted, out);
}

// Round 6
// 348.776 us; speedup vs baseline: 2.0143x; 1.1717x over previous
//
#include <hip/hip_runtime.h>

#define NODES 100000
#define EDGES 1600000
#define BSH 8
#define NBUCK ((NODES + 255) >> BSH)   // 391
#define CHUNK 4096
#define LMAX 8192
// IN_F = HID_F = 128, OUT_F = 64

using bf16x8 = __attribute__((ext_vector_type(8))) short;
using f32x4  = __attribute__((ext_vector_type(4))) float;

__device__ __forceinline__ unsigned short f2b(float f) {
    unsigned u = __builtin_bit_cast(unsigned, f);
    unsigned r = (u + 0x7FFFu + ((u >> 16) & 1u)) >> 16;
    return (unsigned short)r;
}
__device__ __forceinline__ float blo(unsigned u) {
    return __builtin_bit_cast(float, u << 16);
}
__device__ __forceinline__ float bhi(unsigned u) {
    return __builtin_bit_cast(float, u & 0xFFFF0000u);
}

// ---------------- CSR build (no fine-grained global atomics) ----------------

// Coarse bucket histogram: LDS atomics per block, <=512 global atomics/block.
__global__ __launch_bounds__(256) void bhist_kernel(const int* __restrict__ dst,
                                                    int* __restrict__ bucket_cnt) {
    __shared__ int lcnt[512];
    int t = threadIdx.x;
    lcnt[t] = 0; lcnt[t + 256] = 0;
    __syncthreads();
    int base = blockIdx.x * 16384;
    int n = EDGES - base;
    if (n > 16384) n = 16384;
    const int4* d4 = reinterpret_cast<const int4*>(dst + base);
    for (int i = t; i < (n >> 2); i += 256) {
        int4 d = d4[i];
        atomicAdd(&lcnt[d.x >> BSH], 1);
        atomicAdd(&lcnt[d.y >> BSH], 1);
        atomicAdd(&lcnt[d.z >> BSH], 1);
        atomicAdd(&lcnt[d.w >> BSH], 1);
    }
    for (int i = (n & ~3) + t; i < n; i += 256) atomicAdd(&lcnt[dst[base + i] >> BSH], 1);
    __syncthreads();
    if (lcnt[t]) atomicAdd(&bucket_cnt[t], lcnt[t]);
    if (lcnt[t + 256]) atomicAdd(&bucket_cnt[t + 256], lcnt[t + 256]);
}

// One-block scan of bucket counts -> bucket_off (exclusive), init gcursor.
__global__ void bscan_kernel(const int* __restrict__ bucket_cnt, int* __restrict__ bucket_off,
                             int* __restrict__ gcursor, int* __restrict__ row_ptr) {
    __shared__ int sh[512];
    int t = threadIdx.x;
    int v = (t < NBUCK) ? bucket_cnt[t] : 0;
    sh[t] = v;
    __syncthreads();
    for (int off = 1; off < 512; off <<= 1) {
        int x = (t >= off) ? sh[t - off] : 0;
        __syncthreads();
        sh[t] += x;
        __syncthreads();
    }
    int excl = sh[t] - v;
    if (t < NBUCK) { bucket_off[t] = excl; gcursor[t] = excl; }
    if (t == NBUCK) bucket_off[t] = EDGES;
    if (t == 0) row_ptr[NODES] = EDGES;
}

// Bin edges by coarse bucket (dst>>8) via LDS counting sort; write
// bucket-contiguous runs into pairs[] whose bucket regions == CSR regions.
__global__ __launch_bounds__(256) void binscat_kernel(
    const int* __restrict__ src, const int* __restrict__ dst,
    int* __restrict__ gcursor, uint2* __restrict__ pairs) {
    __shared__ int cnt[512];
    __shared__ int scn[512];
    __shared__ int gbs[512];
    __shared__ int cur[512];
    __shared__ uint2 stage[CHUNK];
    int t = threadIdx.x;
    int base = blockIdx.x * CHUNK;
    int n = EDGES - base;
    if (n > CHUNK) n = CHUNK;

    cnt[t] = 0; cnt[t + 256] = 0;
    __syncthreads();

    uint2 my[16];
#pragma unroll
    for (int i = 0; i < 16; ++i) {
        int idx = t + i * 256;
        if (idx < n) {
            int d = dst[base + idx];
            int s = src[base + idx];
            my[i] = make_uint2((unsigned)d, (unsigned)s);
            atomicAdd(&cnt[d >> BSH], 1);
        } else {
            my[i] = make_uint2(0xFFFFFFFFu, 0);
        }
    }
    __syncthreads();
    // inclusive scan cnt -> scn
    scn[t] = cnt[t]; scn[t + 256] = cnt[t + 256];
    __syncthreads();
    for (int off = 1; off < 512; off <<= 1) {
        int a0 = (t >= off) ? scn[t - off] : 0;
        int a1 = (t + 256 >= off) ? scn[t + 256 - off] : 0;
        __syncthreads();
        scn[t] += a0; scn[t + 256] += a1;
        __syncthreads();
    }
    cur[t] = scn[t] - cnt[t];
    cur[t + 256] = scn[t + 256] - cnt[t + 256];
    __syncthreads();
    // place into stage (LDS scatter) + reserve global space per bucket
#pragma unroll
    for (int i = 0; i < 16; ++i) {
        if (my[i].x != 0xFFFFFFFFu) {
            int b = (int)(my[i].x >> BSH);
            int p = atomicAdd(&cur[b], 1);
            stage[p] = my[i];
        }
    }
    for (int b2 = t; b2 < 512; b2 += 256) {
        int c = cnt[b2];
        gbs[b2] = (c > 0 && b2 < NBUCK) ? atomicAdd(&gcursor[b2], c) : 0;
    }
    __syncthreads();
    // coalesced copy-out of bucket-contiguous runs
    for (int idx = t; idx < n; idx += 256) {
        uint2 p = stage[idx];
        int b = (int)(p.x >> BSH);
        int excl = scn[b] - cnt[b];
        pairs[gbs[b] + idx - excl] = p;
    }
}

// One block per bucket: count per-node degrees (LDS), scan, write row_ptr,
// scatter srcs to CSR order inside LDS, contiguous coalesced copy out.
__global__ __launch_bounds__(256) void localsort_kernel(
    const uint2* __restrict__ pairs, const int* __restrict__ bucket_off,
    int* __restrict__ row_ptr, int* __restrict__ src_sorted) {
    __shared__ int cnt[256];
    __shared__ int cur[256];
    __shared__ int stage[LMAX];
    int b = blockIdx.x;
    int t = threadIdx.x;
    int node0 = b << BSH;
    int pbeg = bucket_off[b], pend = bucket_off[b + 1];
    int n = pend - pbeg;
    cnt[t] = 0;
    __syncthreads();
    for (int e = pbeg + t; e < pend; e += 256)
        atomicAdd(&cnt[(int)(pairs[e].x & 255u)], 1);
    __syncthreads();
    int v = cnt[t];
    cur[t] = v;
    __syncthreads();
    for (int off = 1; off < 256; off <<= 1) {
        int x = (t >= off) ? cur[t - off] : 0;
        __syncthreads();
        cur[t] += x;
        __syncthreads();
    }
    int excl = cur[t] - v;
    int node = node0 + t;
    if (node < NODES) row_ptr[node] = pbeg + excl;
    cur[t] = excl;
    __syncthreads();
    if (n <= LMAX) {
        for (int e = pbeg + t; e < pend; e += 256) {
            uint2 p = pairs[e];
            int pos = atomicAdd(&cur[(int)(p.x & 255u)], 1);
            stage[pos] = (int)p.y;
        }
        __syncthreads();
        for (int i = t; i < n; i += 256) src_sorted[pbeg + i] = stage[i];
    } else {  // overflow fallback (not expected for this graph)
        for (int e = pbeg + t; e < pend; e += 256) {
            uint2 p = pairs[e];
            int pos = atomicAdd(&cur[(int)(p.x & 255u)], 1);
            src_sorted[pbeg + pos] = (int)p.y;
        }
    }
}

// ---------------- conversions ----------------

__global__ void f2b_kernel(const float* __restrict__ in, unsigned short* __restrict__ out, int n4) {
    int i = blockIdx.x * 256 + threadIdx.x;
    if (i < n4) {
        float4 v = reinterpret_cast<const float4*>(in)[i];
        uint2 o;
        o.x = (unsigned)f2b(v.x) | ((unsigned)f2b(v.y) << 16);
        o.y = (unsigned)f2b(v.z) | ((unsigned)f2b(v.w) << 16);
        reinterpret_cast<uint2*>(out)[i] = o;
    }
}

// transpose+convert weights: W[k][n] f32 -> Wt[n][k] bf16 (k stride 128)
__global__ void wconv_kernel(const float* __restrict__ W1s, const float* __restrict__ W1n,
                             const float* __restrict__ W2s, const float* __restrict__ W2n,
                             unsigned short* __restrict__ Wt1s, unsigned short* __restrict__ Wt1n,
                             unsigned short* __restrict__ Wt2s, unsigned short* __restrict__ Wt2n) {
    int t = blockIdx.x * 256 + threadIdx.x;
    if (t < 16384) {
        int k = t >> 7, n = t & 127;
        Wt1s[n * 128 + k] = f2b(W1s[t]);
        Wt1n[n * 128 + k] = f2b(W1n[t]);
    }
    if (t < 8192) {
        int k = t >> 6, n = t & 63;
        Wt2s[n * 128 + k] = f2b(W2s[t]);
        Wt2n[n * 128 + k] = f2b(W2n[t]);
    }
}

// ---------------- Mean aggregation (gather via CSR), bf16, wide ----------------
// One wave per node. 16 lanes per edge-row (16B/lane), 4 edge groups, unroll 2:
// 8 row-gathers (2KB) in flight. Cross-group reduce via shfl_xor.

__global__ __launch_bounds__(256) void agg128_bf16(
    const unsigned short* __restrict__ xb, const int* __restrict__ row_ptr,
    const int* __restrict__ srcs, unsigned short* __restrict__ out) {
    int w = (blockIdx.x * 256 + threadIdx.x) >> 6;
    int lane = threadIdx.x & 63;
    if (w >= NODES) return;
    int g = lane >> 4;   // edge group 0..3
    int sl = lane & 15;  // feature sublane: 8 bf16 = 16B
    int beg = row_ptr[w], end = row_ptr[w + 1];

    float a0[8], a1[8];
#pragma unroll
    for (int i = 0; i < 8; ++i) { a0[i] = 0.f; a1[i] = 0.f; }

    const unsigned short* xs = xb + sl * 8;
    int e = beg + g;
    for (; e + 4 < end; e += 8) {
        int s0 = srcs[e];
        int s1 = srcs[e + 4];
        uint4 v0 = *reinterpret_cast<const uint4*>(xs + (size_t)s0 * 128);
        uint4 v1 = *reinterpret_cast<const uint4*>(xs + (size_t)s1 * 128);
        a0[0] += blo(v0.x); a0[1] += bhi(v0.x);
        a0[2] += blo(v0.y); a0[3] += bhi(v0.y);
        a0[4] += blo(v0.z); a0[5] += bhi(v0.z);
        a0[6] += blo(v0.w); a0[7] += bhi(v0.w);
        a1[0] += blo(v1.x); a1[1] += bhi(v1.x);
        a1[2] += blo(v1.y); a1[3] += bhi(v1.y);
        a1[4] += blo(v1.z); a1[5] += bhi(v1.z);
        a1[6] += blo(v1.w); a1[7] += bhi(v1.w);
    }
    if (e < end) {
        int s0 = srcs[e];
        uint4 v0 = *reinterpret_cast<const uint4*>(xs + (size_t)s0 * 128);
        a0[0] += blo(v0.x); a0[1] += bhi(v0.x);
        a0[2] += blo(v0.y); a0[3] += bhi(v0.y);
        a0[4] += blo(v0.z); a0[5] += bhi(v0.z);
        a0[6] += blo(v0.w); a0[7] += bhi(v0.w);
    }
#pragma unroll
    for (int i = 0; i < 8; ++i) {
        float s = a0[i] + a1[i];
        s += __shfl_xor(s, 16, 64);
        s += __shfl_xor(s, 32, 64);
        a0[i] = s;
    }
    if (g == 0) {
        float inv = 1.0f / fmaxf((float)(end - beg), 1.0f);
        uint4 o;
        o.x = (unsigned)f2b(a0[0] * inv) | ((unsigned)f2b(a0[1] * inv) << 16);
        o.y = (unsigned)f2b(a0[2] * inv) | ((unsigned)f2b(a0[3] * inv) << 16);
        o.z = (unsigned)f2b(a0[4] * inv) | ((unsigned)f2b(a0[5] * inv) << 16);
        o.w = (unsigned)f2b(a0[6] * inv) | ((unsigned)f2b(a0[7] * inv) << 16);
        *reinterpret_cast<uint4*>(out + (size_t)w * 128 + sl * 8) = o;
    }
}

// One wave per node, 64 bf16 features (128B/row): 8 lanes per edge-row,
// 8 edge groups, unroll 2 -> 16 rows in flight. Adds mean into f32 out.
__global__ __launch_bounds__(256) void agg64_add(
    const unsigned short* __restrict__ xh, const int* __restrict__ row_ptr,
    const int* __restrict__ srcs, float* __restrict__ out) {
    int w = (blockIdx.x * 256 + threadIdx.x) >> 6;
    int lane = threadIdx.x & 63;
    if (w >= NODES) return;
    int g = lane >> 3;  // edge group 0..7
    int sl = lane & 7;  // feature sublane: 8 bf16 = 16B
    int beg = row_ptr[w], end = row_ptr[w + 1];

    float a0[8], a1[8];
#pragma unroll
    for (int i = 0; i < 8; ++i) { a0[i] = 0.f; a1[i] = 0.f; }

    const unsigned short* xs = xh + sl * 8;
    int e = beg + g;
    for (; e + 8 < end; e += 16) {
        int s0 = srcs[e];
        int s1 = srcs[e + 8];
        uint4 v0 = *reinterpret_cast<const uint4*>(xs + (size_t)s0 * 64);
        uint4 v1 = *reinterpret_cast<const uint4*>(xs + (size_t)s1 * 64);
        a0[0] += blo(v0.x); a0[1] += bhi(v0.x);
        a0[2] += blo(v0.y); a0[3] += bhi(v0.y);
        a0[4] += blo(v0.z); a0[5] += bhi(v0.z);
        a0[6] += blo(v0.w); a0[7] += bhi(v0.w);
        a1[0] += blo(v1.x); a1[1] += bhi(v1.x);
        a1[2] += blo(v1.y); a1[3] += bhi(v1.y);
        a1[4] += blo(v1.z); a1[5] += bhi(v1.z);
        a1[6] += blo(v1.w); a1[7] += bhi(v1.w);
    }
    if (e < end) {
        int s0 = srcs[e];
        uint4 v0 = *reinterpret_cast<const uint4*>(xs + (size_t)s0 * 64);
        a0[0] += blo(v0.x); a0[1] += bhi(v0.x);
        a0[2] += blo(v0.y); a0[3] += bhi(v0.y);
        a0[4] += blo(v0.z); a0[5] += bhi(v0.z);
        a0[6] += blo(v0.w); a0[7] += bhi(v0.w);
    }
#pragma unroll
    for (int i = 0; i < 8; ++i) {
        float s = a0[i] + a1[i];
        s += __shfl_xor(s, 8, 64);
        s += __shfl_xor(s, 16, 64);
        s += __shfl_xor(s, 32, 64);
        a0[i] = s;
    }
    if (g == 0) {
        float inv = 1.0f / fmaxf((float)(end - beg), 1.0f);
        float* op = out + (size_t)w * 64 + sl * 8;
        float4 p0 = *reinterpret_cast<float4*>(op);
        float4 p1 = *reinterpret_cast<float4*>(op + 4);
        p0.x += a0[0] * inv; p0.y += a0[1] * inv;
        p0.z += a0[2] * inv; p0.w += a0[3] * inv;
        p1.x += a0[4] * inv; p1.y += a0[5] * inv;
        p1.z += a0[6] * inv; p1.w += a0[7] * inv;
        *reinterpret_cast<float4*>(op) = p0;
        *reinterpret_cast<float4*>(op + 4) = p1;
    }
}

// ---------------- MFMA GEMMs (bf16 in, K=128) ----------------

__global__ __launch_bounds__(256) void gemm1_mfma(
    const unsigned short* __restrict__ feat, const unsigned short* __restrict__ agg,
    const unsigned short* __restrict__ Wt0, const unsigned short* __restrict__ Wt1,
    const float* __restrict__ bias, unsigned short* __restrict__ x1, int M) {
    int wid = threadIdx.x >> 6, lane = threadIdx.x & 63;
    int l15 = lane & 15, quad = lane >> 4;
    int rb = blockIdx.x * 128 + wid * 32;

    f32x4 acc[2][8];
#pragma unroll
    for (int rg = 0; rg < 2; ++rg)
#pragma unroll
        for (int nt = 0; nt < 8; ++nt) acc[rg][nt] = {0.f, 0.f, 0.f, 0.f};

#pragma unroll
    for (int k0 = 0; k0 < 128; k0 += 32) {
        bf16x8 a0[2], a1[2];
#pragma unroll
        for (int rg = 0; rg < 2; ++rg) {
            int r = rb + rg * 16 + l15;
            if (r >= M) r = M - 1;
            a0[rg] = *reinterpret_cast<const bf16x8*>(feat + (size_t)r * 128 + quad * 8 + k0);
            a1[rg] = *reinterpret_cast<const bf16x8*>(agg + (size_t)r * 128 + quad * 8 + k0);
        }
#pragma unroll
        for (int nt = 0; nt < 8; ++nt) {
            bf16x8 b0 = *reinterpret_cast<const bf16x8*>(Wt0 + (size_t)(nt * 16 + l15) * 128 + quad * 8 + k0);
            bf16x8 b1 = *reinterpret_cast<const bf16x8*>(Wt1 + (size_t)(nt * 16 + l15) * 128 + quad * 8 + k0);
#pragma unroll
            for (int rg = 0; rg < 2; ++rg) {
                acc[rg][nt] = __builtin_amdgcn_mfma_f32_16x16x32_bf16(a0[rg], b0, acc[rg][nt], 0, 0, 0);
                acc[rg][nt] = __builtin_amdgcn_mfma_f32_16x16x32_bf16(a1[rg], b1, acc[rg][nt], 0, 0, 0);
            }
        }
    }

#pragma unroll
    for (int nt = 0; nt < 8; ++nt) {
        int col = nt * 16 + l15;
        float bv = bias[col];
#pragma unroll
        for (int rg = 0; rg < 2; ++rg)
#pragma unroll
            for (int rr = 0; rr < 4; ++rr) {
                int row = rb + rg * 16 + quad * 4 + rr;
                if (row < M) {
                    float v = fmaxf(acc[rg][nt][rr] + bv, 0.f);
                    x1[(size_t)row * 128 + col] = f2b(v);
                }
            }
    }
}

__global__ __launch_bounds__(256) void gemm2_mfma(
    const unsigned short* __restrict__ x1,
    const unsigned short* __restrict__ WtS, const unsigned short* __restrict__ WtN,
    const float* __restrict__ bias, unsigned short* __restrict__ x1h,
    float* __restrict__ outp, int M) {
    int wid = threadIdx.x >> 6, lane = threadIdx.x & 63;
    int l15 = lane & 15, quad = lane >> 4;
    int rb = blockIdx.x * 128 + wid * 32;

    f32x4 accS[2][4], accN[2][4];
#pragma unroll
    for (int rg = 0; rg < 2; ++rg)
#pragma unroll
        for (int nt = 0; nt < 4; ++nt) {
            accS[rg][nt] = {0.f, 0.f, 0.f, 0.f};
            accN[rg][nt] = {0.f, 0.f, 0.f, 0.f};
        }

#pragma unroll
    for (int k0 = 0; k0 < 128; k0 += 32) {
        bf16x8 a[2];
#pragma unroll
        for (int rg = 0; rg < 2; ++rg) {
            int r = rb + rg * 16 + l15;
            if (r >= M) r = M - 1;
            a[rg] = *reinterpret_cast<const bf16x8*>(x1 + (size_t)r * 128 + quad * 8 + k0);
        }
#pragma unroll
        for (int nt = 0; nt < 4; ++nt) {
            bf16x8 bS = *reinterpret_cast<const bf16x8*>(WtS + (size_t)(nt * 16 + l15) * 128 + quad * 8 + k0);
            bf16x8 bN = *reinterpret_cast<const bf16x8*>(WtN + (size_t)(nt * 16 + l15) * 128 + quad * 8 + k0);
#pragma unroll
            for (int rg = 0; rg < 2; ++rg) {
                accS[rg][nt] = __builtin_amdgcn_mfma_f32_16x16x32_bf16(a[rg], bS, accS[rg][nt], 0, 0, 0);
                accN[rg][nt] = __builtin_amdgcn_mfma_f32_16x16x32_bf16(a[rg], bN, accN[rg][nt], 0, 0, 0);
            }
        }
    }

#pragma unroll
    for (int nt = 0; nt < 4; ++nt) {
        int col = nt * 16 + l15;
        float bv = bias[col];
#pragma unroll
        for (int rg = 0; rg < 2; ++rg)
#pragma unroll
            for (int rr = 0; rr < 4; ++rr) {
                int row = rb + rg * 16 + quad * 4 + rr;
                if (row < M) {
                    x1h[(size_t)row * 64 + col] = f2b(accN[rg][nt][rr]);
                    outp[(size_t)row * 64 + col] = accS[rg][nt][rr] + bv;
                }
            }
    }
}

// ---------------- launch ----------------

extern "C" void kernel_launch(void* const* d_in, const int* in_sizes, int n_in,
                              void* d_out, int out_size, void* d_ws, size_t ws_size,
                              hipStream_t stream) {
    const float* features = (const float*)d_in[0];
    const int* esrc = (const int*)d_in[1];
    const int* edst = (const int*)d_in[2];
    const float* W1s = (const float*)d_in[3];
    const float* W1n = (const float*)d_in[4];
    const float* b1  = (const float*)d_in[5];
    const float* W2s = (const float*)d_in[6];
    const float* W2n = (const float*)d_in[7];
    const float* b2  = (const float*)d_in[8];
    float* out = (float*)d_out;

    char* ws = (char*)d_ws;
    size_t off = 0;
    auto alloc = [&](size_t bytes) {
        void* p = ws + off;
        off += (bytes + 255) & ~(size_t)255;
        return p;
    };
    int* bucket_cnt = (int*)alloc(512 * 4);
    int* bucket_off = (int*)alloc(512 * 4);
    int* gcursor    = (int*)alloc(512 * 4);
    int* row_ptr    = (int*)alloc((size_t)(NODES + 1) * 4);
    int* src_sorted = (int*)alloc((size_t)EDGES * 4);
    uint2* pairs    = (uint2*)alloc((size_t)EDGES * 8);
    unsigned short* featb = (unsigned short*)alloc((size_t)NODES * 128 * 2);
    unsigned short* agg1  = (unsigned short*)alloc((size_t)NODES * 128 * 2);
    unsigned short* x1    = (unsigned short*)alloc((size_t)NODES * 128 * 2);
    unsigned short* x1h   = (unsigned short*)alloc((size_t)NODES * 64 * 2);
    unsigned short* Wt1s  = (unsigned short*)alloc(16384 * 2);
    unsigned short* Wt1n  = (unsigned short*)alloc(16384 * 2);
    unsigned short* Wt2s  = (unsigned short*)alloc(8192 * 2);
    unsigned short* Wt2n  = (unsigned short*)alloc(8192 * 2);

    // conversions (independent of CSR build)
    f2b_kernel<<<(NODES * 128 / 4 + 255) / 256, 256, 0, stream>>>(features, featb, NODES * 128 / 4);
    wconv_kernel<<<64, 256, 0, stream>>>(W1s, W1n, W2s, W2n, Wt1s, Wt1n, Wt2s, Wt2n);

    // CSR build: coarse hist -> bucket scan -> bucket bin -> per-bucket sort
    hipMemsetAsync(bucket_cnt, 0, 512 * 4, stream);
    bhist_kernel<<<(EDGES + 16383) / 16384, 256, 0, stream>>>(edst, bucket_cnt);
    bscan_kernel<<<1, 512, 0, stream>>>(bucket_cnt, bucket_off, gcursor, row_ptr);
    binscat_kernel<<<(EDGES + CHUNK - 1) / CHUNK, 256, 0, stream>>>(esrc, edst, gcursor, pairs);
    localsort_kernel<<<NBUCK, 256, 0, stream>>>(pairs, bucket_off, row_ptr, src_sorted);

    // layer 1
    agg128_bf16<<<(NODES * 64 + 255) / 256, 256, 0, stream>>>(featb, row_ptr, src_sorted, agg1);
    gemm1_mfma<<<(NODES + 127) / 128, 256, 0, stream>>>(featb, agg1, Wt1s, Wt1n, b1, x1, NODES);

    // layer 2: x1h = x1@W2n; out = x1@W2s + b2; then out += mean-neigh(x1h)
    gemm2_mfma<<<(NODES + 127) / 128, 256, 0, stream>>>(x1, Wt2s, Wt2n, b2, x1h, out, NODES);
    agg64_add<<<(NODES * 64 + 255) / 256, 256, 0, stream>>>(x1h, row_ptr, src_sorted, out);
}

// Round 7
// 306.426 us; speedup vs baseline: 2.2927x; 1.1382x over previous
//
#include <hip/hip_runtime.h>

#define NODES 100000
#define EDGES 1600000
#define BSH 8
#define NBUCK ((NODES + 255) >> BSH)   // 391
#define CHUNK 4096
#define LMAX 8192
#define MCHUNKS ((NODES + 31) / 32)    // 3125
// IN_F = HID_F = 128, OUT_F = 64

using bf16x8 = __attribute__((ext_vector_type(8))) short;
using f32x4  = __attribute__((ext_vector_type(4))) float;

__device__ __forceinline__ unsigned short f2b(float f) {
    unsigned u = __builtin_bit_cast(unsigned, f);
    unsigned r = (u + 0x7FFFu + ((u >> 16) & 1u)) >> 16;
    return (unsigned short)r;
}
__device__ __forceinline__ float blo(unsigned u) {
    return __builtin_bit_cast(float, u << 16);
}
__device__ __forceinline__ float bhi(unsigned u) {
    return __builtin_bit_cast(float, u & 0xFFFF0000u);
}

// ---------------- CSR build (no fine-grained global atomics) ----------------

__global__ __launch_bounds__(256) void bhist_kernel(const int* __restrict__ dst,
                                                    int* __restrict__ bucket_cnt) {
    __shared__ int lcnt[512];
    int t = threadIdx.x;
    lcnt[t] = 0; lcnt[t + 256] = 0;
    __syncthreads();
    int base = blockIdx.x * 16384;
    int n = EDGES - base;
    if (n > 16384) n = 16384;
    const int4* d4 = reinterpret_cast<const int4*>(dst + base);
    for (int i = t; i < (n >> 2); i += 256) {
        int4 d = d4[i];
        atomicAdd(&lcnt[d.x >> BSH], 1);
        atomicAdd(&lcnt[d.y >> BSH], 1);
        atomicAdd(&lcnt[d.z >> BSH], 1);
        atomicAdd(&lcnt[d.w >> BSH], 1);
    }
    for (int i = (n & ~3) + t; i < n; i += 256) atomicAdd(&lcnt[dst[base + i] >> BSH], 1);
    __syncthreads();
    if (lcnt[t]) atomicAdd(&bucket_cnt[t], lcnt[t]);
    if (lcnt[t + 256]) atomicAdd(&bucket_cnt[t + 256], lcnt[t + 256]);
}

__global__ void bscan_kernel(const int* __restrict__ bucket_cnt, int* __restrict__ bucket_off,
                             int* __restrict__ gcursor, int* __restrict__ row_ptr) {
    __shared__ int sh[512];
    int t = threadIdx.x;
    int v = (t < NBUCK) ? bucket_cnt[t] : 0;
    sh[t] = v;
    __syncthreads();
    for (int off = 1; off < 512; off <<= 1) {
        int x = (t >= off) ? sh[t - off] : 0;
        __syncthreads();
        sh[t] += x;
        __syncthreads();
    }
    int excl = sh[t] - v;
    if (t < NBUCK) { bucket_off[t] = excl; gcursor[t] = excl; }
    if (t == NBUCK) bucket_off[t] = EDGES;
    if (t == 0) row_ptr[NODES] = EDGES;
}

__global__ __launch_bounds__(256) void binscat_kernel(
    const int* __restrict__ src, const int* __restrict__ dst,
    int* __restrict__ gcursor, uint2* __restrict__ pairs) {
    __shared__ int cnt[512];
    __shared__ int scn[512];
    __shared__ int gbs[512];
    __shared__ int cur[512];
    __shared__ uint2 stage[CHUNK];
    int t = threadIdx.x;
    int base = blockIdx.x * CHUNK;
    int n = EDGES - base;
    if (n > CHUNK) n = CHUNK;

    cnt[t] = 0; cnt[t + 256] = 0;
    __syncthreads();

    uint2 my[16];
#pragma unroll
    for (int i = 0; i < 16; ++i) {
        int idx = t + i * 256;
        if (idx < n) {
            int d = dst[base + idx];
            int s = src[base + idx];
            my[i] = make_uint2((unsigned)d, (unsigned)s);
            atomicAdd(&cnt[d >> BSH], 1);
        } else {
            my[i] = make_uint2(0xFFFFFFFFu, 0);
        }
    }
    __syncthreads();
    scn[t] = cnt[t]; scn[t + 256] = cnt[t + 256];
    __syncthreads();
    for (int off = 1; off < 512; off <<= 1) {
        int a0 = (t >= off) ? scn[t - off] : 0;
        int a1 = (t + 256 >= off) ? scn[t + 256 - off] : 0;
        __syncthreads();
        scn[t] += a0; scn[t + 256] += a1;
        __syncthreads();
    }
    cur[t] = scn[t] - cnt[t];
    cur[t + 256] = scn[t + 256] - cnt[t + 256];
    __syncthreads();
#pragma unroll
    for (int i = 0; i < 16; ++i) {
        if (my[i].x != 0xFFFFFFFFu) {
            int b = (int)(my[i].x >> BSH);
            int p = atomicAdd(&cur[b], 1);
            stage[p] = my[i];
        }
    }
    for (int b2 = t; b2 < 512; b2 += 256) {
        int c = cnt[b2];
        gbs[b2] = (c > 0 && b2 < NBUCK) ? atomicAdd(&gcursor[b2], c) : 0;
    }
    __syncthreads();
    for (int idx = t; idx < n; idx += 256) {
        uint2 p = stage[idx];
        int b = (int)(p.x >> BSH);
        int excl = scn[b] - cnt[b];
        pairs[gbs[b] + idx - excl] = p;
    }
}

__global__ __launch_bounds__(256) void localsort_kernel(
    const uint2* __restrict__ pairs, const int* __restrict__ bucket_off,
    int* __restrict__ row_ptr, int* __restrict__ src_sorted) {
    __shared__ int cnt[256];
    __shared__ int cur[256];
    __shared__ int stage[LMAX];
    int b = blockIdx.x;
    int t = threadIdx.x;
    int node0 = b << BSH;
    int pbeg = bucket_off[b], pend = bucket_off[b + 1];
    int n = pend - pbeg;
    cnt[t] = 0;
    __syncthreads();
    for (int e = pbeg + t; e < pend; e += 256)
        atomicAdd(&cnt[(int)(pairs[e].x & 255u)], 1);
    __syncthreads();
    int v = cnt[t];
    cur[t] = v;
    __syncthreads();
    for (int off = 1; off < 256; off <<= 1) {
        int x = (t >= off) ? cur[t - off] : 0;
        __syncthreads();
        cur[t] += x;
        __syncthreads();
    }
    int excl = cur[t] - v;
    int node = node0 + t;
    if (node < NODES) row_ptr[node] = pbeg + excl;
    cur[t] = excl;
    __syncthreads();
    if (n <= LMAX) {
        for (int e = pbeg + t; e < pend; e += 256) {
            uint2 p = pairs[e];
            int pos = atomicAdd(&cur[(int)(p.x & 255u)], 1);
            stage[pos] = (int)p.y;
        }
        __syncthreads();
        for (int i = t; i < n; i += 256) src_sorted[pbeg + i] = stage[i];
    } else {
        for (int e = pbeg + t; e < pend; e += 256) {
            uint2 p = pairs[e];
            int pos = atomicAdd(&cur[(int)(p.x & 255u)], 1);
            src_sorted[pbeg + pos] = (int)p.y;
        }
    }
}

// ---------------- conversions ----------------

__global__ void f2b_kernel(const float* __restrict__ in, unsigned short* __restrict__ out, int n4) {
    int i = blockIdx.x * 256 + threadIdx.x;
    if (i < n4) {
        float4 v = reinterpret_cast<const float4*>(in)[i];
        uint2 o;
        o.x = (unsigned)f2b(v.x) | ((unsigned)f2b(v.y) << 16);
        o.y = (unsigned)f2b(v.z) | ((unsigned)f2b(v.w) << 16);
        reinterpret_cast<uint2*>(out)[i] = o;
    }
}

__global__ void wconv_kernel(const float* __restrict__ W1s, const float* __restrict__ W1n,
                             const float* __restrict__ W2s, const float* __restrict__ W2n,
                             unsigned short* __restrict__ Wt1s, unsigned short* __restrict__ Wt1n,
                             unsigned short* __restrict__ Wt2s, unsigned short* __restrict__ Wt2n) {
    int t = blockIdx.x * 256 + threadIdx.x;
    if (t < 16384) {
        int k = t >> 7, n = t & 127;
        Wt1s[n * 128 + k] = f2b(W1s[t]);
        Wt1n[n * 128 + k] = f2b(W1n[t]);
    }
    if (t < 8192) {
        int k = t >> 6, n = t & 63;
        Wt2s[n * 128 + k] = f2b(W2s[t]);
        Wt2n[n * 128 + k] = f2b(W2n[t]);
    }
}

// ---------------- Mean aggregation (gather via CSR), bf16, wide ----------------

__global__ __launch_bounds__(256) void agg128_bf16(
    const unsigned short* __restrict__ xb, const int* __restrict__ row_ptr,
    const int* __restrict__ srcs, unsigned short* __restrict__ out) {
    int w = (blockIdx.x * 256 + threadIdx.x) >> 6;
    int lane = threadIdx.x & 63;
    if (w >= NODES) return;
    int g = lane >> 4;   // edge group 0..3
    int sl = lane & 15;  // feature sublane: 8 bf16 = 16B
    int beg = row_ptr[w], end = row_ptr[w + 1];

    float a0[8], a1[8];
#pragma unroll
    for (int i = 0; i < 8; ++i) { a0[i] = 0.f; a1[i] = 0.f; }

    const unsigned short* xs = xb + sl * 8;
    int e = beg + g;
    for (; e + 4 < end; e += 8) {
        int s0 = srcs[e];
        int s1 = srcs[e + 4];
        uint4 v0 = *reinterpret_cast<const uint4*>(xs + (size_t)s0 * 128);
        uint4 v1 = *reinterpret_cast<const uint4*>(xs + (size_t)s1 * 128);
        a0[0] += blo(v0.x); a0[1] += bhi(v0.x);
        a0[2] += blo(v0.y); a0[3] += bhi(v0.y);
        a0[4] += blo(v0.z); a0[5] += bhi(v0.z);
        a0[6] += blo(v0.w); a0[7] += bhi(v0.w);
        a1[0] += blo(v1.x); a1[1] += bhi(v1.x);
        a1[2] += blo(v1.y); a1[3] += bhi(v1.y);
        a1[4] += blo(v1.z); a1[5] += bhi(v1.z);
        a1[6] += blo(v1.w); a1[7] += bhi(v1.w);
    }
    if (e < end) {
        int s0 = srcs[e];
        uint4 v0 = *reinterpret_cast<const uint4*>(xs + (size_t)s0 * 128);
        a0[0] += blo(v0.x); a0[1] += bhi(v0.x);
        a0[2] += blo(v0.y); a0[3] += bhi(v0.y);
        a0[4] += blo(v0.z); a0[5] += bhi(v0.z);
        a0[6] += blo(v0.w); a0[7] += bhi(v0.w);
    }
#pragma unroll
    for (int i = 0; i < 8; ++i) {
        float s = a0[i] + a1[i];
        s += __shfl_xor(s, 16, 64);
        s += __shfl_xor(s, 32, 64);
        a0[i] = s;
    }
    if (g == 0) {
        float inv = 1.0f / fmaxf((float)(end - beg), 1.0f);
        uint4 o;
        o.x = (unsigned)f2b(a0[0] * inv) | ((unsigned)f2b(a0[1] * inv) << 16);
        o.y = (unsigned)f2b(a0[2] * inv) | ((unsigned)f2b(a0[3] * inv) << 16);
        o.z = (unsigned)f2b(a0[4] * inv) | ((unsigned)f2b(a0[5] * inv) << 16);
        o.w = (unsigned)f2b(a0[6] * inv) | ((unsigned)f2b(a0[7] * inv) << 16);
        *reinterpret_cast<uint4*>(out + (size_t)w * 128 + sl * 8) = o;
    }
}

__global__ __launch_bounds__(256) void agg64_add(
    const unsigned short* __restrict__ xh, const int* __restrict__ row_ptr,
    const int* __restrict__ srcs, float* __restrict__ out) {
    int w = (blockIdx.x * 256 + threadIdx.x) >> 6;
    int lane = threadIdx.x & 63;
    if (w >= NODES) return;
    int g = lane >> 3;  // edge group 0..7
    int sl = lane & 7;  // feature sublane: 8 bf16 = 16B
    int beg = row_ptr[w], end = row_ptr[w + 1];

    float a0[8], a1[8];
#pragma unroll
    for (int i = 0; i < 8; ++i) { a0[i] = 0.f; a1[i] = 0.f; }

    const unsigned short* xs = xh + sl * 8;
    int e = beg + g;
    for (; e + 8 < end; e += 16) {
        int s0 = srcs[e];
        int s1 = srcs[e + 8];
        uint4 v0 = *reinterpret_cast<const uint4*>(xs + (size_t)s0 * 64);
        uint4 v1 = *reinterpret_cast<const uint4*>(xs + (size_t)s1 * 64);
        a0[0] += blo(v0.x); a0[1] += bhi(v0.x);
        a0[2] += blo(v0.y); a0[3] += bhi(v0.y);
        a0[4] += blo(v0.z); a0[5] += bhi(v0.z);
        a0[6] += blo(v0.w); a0[7] += bhi(v0.w);
        a1[0] += blo(v1.x); a1[1] += bhi(v1.x);
        a1[2] += blo(v1.y); a1[3] += bhi(v1.y);
        a1[4] += blo(v1.z); a1[5] += bhi(v1.z);
        a1[6] += blo(v1.w); a1[7] += bhi(v1.w);
    }
    if (e < end) {
        int s0 = srcs[e];
        uint4 v0 = *reinterpret_cast<const uint4*>(xs + (size_t)s0 * 64);
        a0[0] += blo(v0.x); a0[1] += bhi(v0.x);
        a0[2] += blo(v0.y); a0[3] += bhi(v0.y);
        a0[4] += blo(v0.z); a0[5] += bhi(v0.z);
        a0[6] += blo(v0.w); a0[7] += bhi(v0.w);
    }
#pragma unroll
    for (int i = 0; i < 8; ++i) {
        float s = a0[i] + a1[i];
        s += __shfl_xor(s, 8, 64);
        s += __shfl_xor(s, 16, 64);
        s += __shfl_xor(s, 32, 64);
        a0[i] = s;
    }
    if (g == 0) {
        float inv = 1.0f / fmaxf((float)(end - beg), 1.0f);
        float* op = out + (size_t)w * 64 + sl * 8;
        float4 p0 = *reinterpret_cast<float4*>(op);
        float4 p1 = *reinterpret_cast<float4*>(op + 4);
        p0.x += a0[0] * inv; p0.y += a0[1] * inv;
        p0.z += a0[2] * inv; p0.w += a0[3] * inv;
        p1.x += a0[4] * inv; p1.y += a0[5] * inv;
        p1.z += a0[6] * inv; p1.w += a0[7] * inv;
        *reinterpret_cast<float4*>(op) = p0;
        *reinterpret_cast<float4*>(op + 4) = p1;
    }
}

// ---------------- Fused MLP: x1 = relu(feat@W1s + agg@W1n + b1);
//                  x1h = x1@W2n; outp = x1@W2s + b2.
// Persistent B in registers (wave owns a col-strip), grid-stride over 32-row
// chunks, x1 round-trips through LDS only (never global).

__global__ __launch_bounds__(256, 2) void fused_mlp(
    const unsigned short* __restrict__ featb, const unsigned short* __restrict__ agg,
    const unsigned short* __restrict__ Wt1s, const unsigned short* __restrict__ Wt1n,
    const float* __restrict__ b1, const unsigned short* __restrict__ Wt2s,
    const unsigned short* __restrict__ Wt2n, const float* __restrict__ b2,
    unsigned short* __restrict__ x1h, float* __restrict__ outp) {
    __shared__ __align__(16) unsigned short x1t[32 * 136];  // pad 136 -> uniform banks
    int wid = threadIdx.x >> 6, lane = threadIdx.x & 63;
    int l15 = lane & 15, quad = lane >> 4;

    // persistent B fragments: W1 strip = cols [wid*32, wid*32+32)
    bf16x8 B1s[2][4], B1n[2][4];  // [nt2][k0]
#pragma unroll
    for (int nt = 0; nt < 2; ++nt) {
        int col = wid * 32 + nt * 16 + l15;
#pragma unroll
        for (int k = 0; k < 4; ++k) {
            B1s[nt][k] = *reinterpret_cast<const bf16x8*>(Wt1s + (size_t)col * 128 + k * 32 + quad * 8);
            B1n[nt][k] = *reinterpret_cast<const bf16x8*>(Wt1n + (size_t)col * 128 + k * 32 + quad * 8);
        }
    }
    // W2 strip = cols [wid*16, wid*16+16)
    bf16x8 B2s[4], B2n[4];
    {
        int col2 = wid * 16 + l15;
#pragma unroll
        for (int k = 0; k < 4; ++k) {
            B2s[k] = *reinterpret_cast<const bf16x8*>(Wt2s + (size_t)col2 * 128 + k * 32 + quad * 8);
            B2n[k] = *reinterpret_cast<const bf16x8*>(Wt2n + (size_t)col2 * 128 + k * 32 + quad * 8);
        }
    }
    float bv1[2];
    bv1[0] = b1[wid * 32 + l15];
    bv1[1] = b1[wid * 32 + 16 + l15];
    float bv2 = b2[wid * 16 + l15];

    for (int c = blockIdx.x; c < MCHUNKS; c += gridDim.x) {
        int rbase = c * 32;
        // A-loads: 2 rg x 4 k chunks x 2 matrices, all independent & in flight
        bf16x8 Af[2][4], Aa[2][4];
#pragma unroll
        for (int rg = 0; rg < 2; ++rg) {
            int r = rbase + rg * 16 + l15;
            if (r >= NODES) r = NODES - 1;
            const unsigned short* fp = featb + (size_t)r * 128 + quad * 8;
            const unsigned short* ap = agg + (size_t)r * 128 + quad * 8;
#pragma unroll
            for (int k = 0; k < 4; ++k) {
                Af[rg][k] = *reinterpret_cast<const bf16x8*>(fp + k * 32);
                Aa[rg][k] = *reinterpret_cast<const bf16x8*>(ap + k * 32);
            }
        }
        f32x4 acc[2][2];  // [rg][nt2]
#pragma unroll
        for (int rg = 0; rg < 2; ++rg)
#pragma unroll
            for (int nt = 0; nt < 2; ++nt) acc[rg][nt] = {0.f, 0.f, 0.f, 0.f};
#pragma unroll
        for (int k = 0; k < 4; ++k)
#pragma unroll
            for (int nt = 0; nt < 2; ++nt)
#pragma unroll
                for (int rg = 0; rg < 2; ++rg) {
                    acc[rg][nt] = __builtin_amdgcn_mfma_f32_16x16x32_bf16(Af[rg][k], B1s[nt][k], acc[rg][nt], 0, 0, 0);
                    acc[rg][nt] = __builtin_amdgcn_mfma_f32_16x16x32_bf16(Aa[rg][k], B1n[nt][k], acc[rg][nt], 0, 0, 0);
                }
        // bias + relu + bf16 -> LDS x1 tile (C-layout: row=rg*16+quad*4+rr, col strip)
#pragma unroll
        for (int nt = 0; nt < 2; ++nt)
#pragma unroll
            for (int rg = 0; rg < 2; ++rg)
#pragma unroll
                for (int rr = 0; rr < 4; ++rr) {
                    float v = fmaxf(acc[rg][nt][rr] + bv1[nt], 0.f);
                    x1t[(rg * 16 + quad * 4 + rr) * 136 + wid * 32 + nt * 16 + l15] = f2b(v);
                }
        __syncthreads();
        // phase 3: x1 tile as A-operand (row=l15-based), W2 strips
        f32x4 acc2s[2], acc2n[2];  // [rg]
#pragma unroll
        for (int rg = 0; rg < 2; ++rg) { acc2s[rg] = {0.f, 0.f, 0.f, 0.f}; acc2n[rg] = {0.f, 0.f, 0.f, 0.f}; }
#pragma unroll
        for (int k = 0; k < 4; ++k)
#pragma unroll
            for (int rg = 0; rg < 2; ++rg) {
                bf16x8 a = *reinterpret_cast<const bf16x8*>(&x1t[(rg * 16 + l15) * 136 + k * 32 + quad * 8]);
                acc2s[rg] = __builtin_amdgcn_mfma_f32_16x16x32_bf16(a, B2s[k], acc2s[rg], 0, 0, 0);
                acc2n[rg] = __builtin_amdgcn_mfma_f32_16x16x32_bf16(a, B2n[k], acc2n[rg], 0, 0, 0);
            }
        int col2 = wid * 16 + l15;
#pragma unroll
        for (int rg = 0; rg < 2; ++rg)
#pragma unroll
            for (int rr = 0; rr < 4; ++rr) {
                int row = rbase + rg * 16 + quad * 4 + rr;
                if (row < NODES) {
                    x1h[(size_t)row * 64 + col2] = f2b(acc2n[rg][rr]);
                    outp[(size_t)row * 64 + col2] = acc2s[rg][rr] + bv2;
                }
            }
        __syncthreads();  // protect x1t before next chunk overwrites
    }
}

// ---------------- launch ----------------

extern "C" void kernel_launch(void* const* d_in, const int* in_sizes, int n_in,
                              void* d_out, int out_size, void* d_ws, size_t ws_size,
                              hipStream_t stream) {
    const float* features = (const float*)d_in[0];
    const int* esrc = (const int*)d_in[1];
    const int* edst = (const int*)d_in[2];
    const float* W1s = (const float*)d_in[3];
    const float* W1n = (const float*)d_in[4];
    const float* b1  = (const float*)d_in[5];
    const float* W2s = (const float*)d_in[6];
    const float* W2n = (const float*)d_in[7];
    const float* b2  = (const float*)d_in[8];
    float* out = (float*)d_out;

    char* ws = (char*)d_ws;
    size_t off = 0;
    auto alloc = [&](size_t bytes) {
        void* p = ws + off;
        off += (bytes + 255) & ~(size_t)255;
        return p;
    };
    int* bucket_cnt = (int*)alloc(512 * 4);
    int* bucket_off = (int*)alloc(512 * 4);
    int* gcursor    = (int*)alloc(512 * 4);
    int* row_ptr    = (int*)alloc((size_t)(NODES + 1) * 4);
    int* src_sorted = (int*)alloc((size_t)EDGES * 4);
    uint2* pairs    = (uint2*)alloc((size_t)EDGES * 8);
    unsigned short* featb = (unsigned short*)alloc((size_t)NODES * 128 * 2);
    unsigned short* agg1  = (unsigned short*)alloc((size_t)NODES * 128 * 2);
    unsigned short* x1h   = (unsigned short*)alloc((size_t)NODES * 64 * 2);
    unsigned short* Wt1s  = (unsigned short*)alloc(16384 * 2);
    unsigned short* Wt1n  = (unsigned short*)alloc(16384 * 2);
    unsigned short* Wt2s  = (unsigned short*)alloc(8192 * 2);
    unsigned short* Wt2n  = (unsigned short*)alloc(8192 * 2);

    // conversions (independent of CSR build)
    f2b_kernel<<<(NODES * 128 / 4 + 255) / 256, 256, 0, stream>>>(features, featb, NODES * 128 / 4);
    wconv_kernel<<<64, 256, 0, stream>>>(W1s, W1n, W2s, W2n, Wt1s, Wt1n, Wt2s, Wt2n);

    // CSR build: coarse hist -> bucket scan -> bucket bin -> per-bucket sort
    hipMemsetAsync(bucket_cnt, 0, 512 * 4, stream);
    bhist_kernel<<<(EDGES + 16383) / 16384, 256, 0, stream>>>(edst, bucket_cnt);
    bscan_kernel<<<1, 512, 0, stream>>>(bucket_cnt, bucket_off, gcursor, row_ptr);
    binscat_kernel<<<(EDGES + CHUNK - 1) / CHUNK, 256, 0, stream>>>(esrc, edst, gcursor, pairs);
    localsort_kernel<<<NBUCK, 256, 0, stream>>>(pairs, bucket_off, row_ptr, src_sorted);

    // layer 1 aggregation
    agg128_bf16<<<(NODES * 64 + 255) / 256, 256, 0, stream>>>(featb, row_ptr, src_sorted, agg1);

    // fused: x1 (in LDS) -> x1h bf16 + out f32 (self part + bias)
    fused_mlp<<<1024, 256, 0, stream>>>(featb, agg1, Wt1s, Wt1n, b1, Wt2s, Wt2n, b2, x1h, out);

    // out += mean-neigh(x1h)
    agg64_add<<<(NODES * 64 + 255) / 256, 256, 0, stream>>>(x1h, row_ptr, src_sorted, out);
}

// Round 9
// 288.779 us; speedup vs baseline: 2.4328x; 1.0611x over previous
//
#include <hip/hip_runtime.h>

#define NODES 100000
#define EDGES 1600000
#define BSH 8
#define NBUCK ((NODES + 255) >> BSH)   // 391
#define CHUNK 4096
#define LMAX 8192
#define MCHUNKS ((NODES + 31) / 32)    // 3125
// IN_F = HID_F = 128, OUT_F = 64

using bf16x8 = __attribute__((ext_vector_type(8))) short;
using f32x4  = __attribute__((ext_vector_type(4))) float;
using f32x2  = __attribute__((ext_vector_type(2))) float;

__device__ __forceinline__ unsigned short f2b(float f) {
    unsigned u = __builtin_bit_cast(unsigned, f);
    unsigned r = (u + 0x7FFFu + ((u >> 16) & 1u)) >> 16;
    return (unsigned short)r;
}

// unpack 8 fp8 (uint2) and accumulate into a[0..7]
__device__ __forceinline__ void add_fp8x8(float* a, uint2 v) {
    f32x2 p0 = __builtin_amdgcn_cvt_pk_f32_fp8((int)v.x, false);
    f32x2 p1 = __builtin_amdgcn_cvt_pk_f32_fp8((int)v.x, true);
    f32x2 p2 = __builtin_amdgcn_cvt_pk_f32_fp8((int)v.y, false);
    f32x2 p3 = __builtin_amdgcn_cvt_pk_f32_fp8((int)v.y, true);
    a[0] += p0[0]; a[1] += p0[1]; a[2] += p1[0]; a[3] += p1[1];
    a[4] += p2[0]; a[5] += p2[1]; a[6] += p3[0]; a[7] += p3[1];
}

// ---------------- CSR build (no fine-grained global atomics) ----------------

__global__ __launch_bounds__(256) void bhist_kernel(const int* __restrict__ dst,
                                                    int* __restrict__ bucket_cnt) {
    __shared__ int lcnt[512];
    int t = threadIdx.x;
    lcnt[t] = 0; lcnt[t + 256] = 0;
    __syncthreads();
    int base = blockIdx.x * 16384;
    int n = EDGES - base;
    if (n > 16384) n = 16384;
    const int4* d4 = reinterpret_cast<const int4*>(dst + base);
    for (int i = t; i < (n >> 2); i += 256) {
        int4 d = d4[i];
        atomicAdd(&lcnt[d.x >> BSH], 1);
        atomicAdd(&lcnt[d.y >> BSH], 1);
        atomicAdd(&lcnt[d.z >> BSH], 1);
        atomicAdd(&lcnt[d.w >> BSH], 1);
    }
    for (int i = (n & ~3) + t; i < n; i += 256) atomicAdd(&lcnt[dst[base + i] >> BSH], 1);
    __syncthreads();
    if (lcnt[t]) atomicAdd(&bucket_cnt[t], lcnt[t]);
    if (lcnt[t + 256]) atomicAdd(&bucket_cnt[t + 256], lcnt[t + 256]);
}

__global__ void bscan_kernel(const int* __restrict__ bucket_cnt, int* __restrict__ bucket_off,
                             int* __restrict__ gcursor, int* __restrict__ row_ptr) {
    __shared__ int sh[512];
    int t = threadIdx.x;
    int v = (t < NBUCK) ? bucket_cnt[t] : 0;
    sh[t] = v;
    __syncthreads();
    for (int off = 1; off < 512; off <<= 1) {
        int x = (t >= off) ? sh[t - off] : 0;
        __syncthreads();
        sh[t] += x;
        __syncthreads();
    }
    int excl = sh[t] - v;
    if (t < NBUCK) { bucket_off[t] = excl; gcursor[t] = excl; }
    if (t == NBUCK) bucket_off[t] = EDGES;
    if (t == 0) row_ptr[NODES] = EDGES;
}

// Bin edges by coarse bucket; write packed (dst&255)<<24|src runs.
__global__ __launch_bounds__(256) void binscat_kernel(
    const int* __restrict__ src, const int* __restrict__ dst,
    int* __restrict__ gcursor, unsigned* __restrict__ pairs) {
    __shared__ int cnt[512];
    __shared__ int scn[512];
    __shared__ int gbs[512];
    __shared__ int cur[512];
    __shared__ uint2 stage[CHUNK];
    int t = threadIdx.x;
    int base = blockIdx.x * CHUNK;
    int n = EDGES - base;
    if (n > CHUNK) n = CHUNK;

    cnt[t] = 0; cnt[t + 256] = 0;
    __syncthreads();

    uint2 my[16];
#pragma unroll
    for (int i = 0; i < 16; ++i) {
        int idx = t + i * 256;
        if (idx < n) {
            int d = dst[base + idx];
            int s = src[base + idx];
            my[i] = make_uint2((unsigned)d, (unsigned)s);
            atomicAdd(&cnt[d >> BSH], 1);
        } else {
            my[i] = make_uint2(0xFFFFFFFFu, 0);
        }
    }
    __syncthreads();
    scn[t] = cnt[t]; scn[t + 256] = cnt[t + 256];
    __syncthreads();
    for (int off = 1; off < 512; off <<= 1) {
        int a0 = (t >= off) ? scn[t - off] : 0;
        int a1 = (t + 256 >= off) ? scn[t + 256 - off] : 0;
        __syncthreads();
        scn[t] += a0; scn[t + 256] += a1;
        __syncthreads();
    }
    cur[t] = scn[t] - cnt[t];
    cur[t + 256] = scn[t + 256] - cnt[t + 256];
    __syncthreads();
#pragma unroll
    for (int i = 0; i < 16; ++i) {
        if (my[i].x != 0xFFFFFFFFu) {
            int b = (int)(my[i].x >> BSH);
            int p = atomicAdd(&cur[b], 1);
            stage[p] = my[i];
        }
    }
    for (int b2 = t; b2 < 512; b2 += 256) {
        int c = cnt[b2];
        gbs[b2] = (c > 0 && b2 < NBUCK) ? atomicAdd(&gcursor[b2], c) : 0;
    }
    __syncthreads();
    for (int idx = t; idx < n; idx += 256) {
        uint2 p = stage[idx];
        int b = (int)(p.x >> BSH);
        int excl = scn[b] - cnt[b];
        pairs[gbs[b] + idx - excl] = ((p.x & 255u) << 24) | p.y;
    }
}

__global__ __launch_bounds__(256) void localsort_kernel(
    const unsigned* __restrict__ pairs, const int* __restrict__ bucket_off,
    int* __restrict__ row_ptr, int* __restrict__ src_sorted) {
    __shared__ int cnt[256];
    __shared__ int cur[256];
    __shared__ int stage[LMAX];
    int b = blockIdx.x;
    int t = threadIdx.x;
    int node0 = b << BSH;
    int pbeg = bucket_off[b], pend = bucket_off[b + 1];
    int n = pend - pbeg;
    cnt[t] = 0;
    __syncthreads();
    for (int e = pbeg + t; e < pend; e += 256)
        atomicAdd(&cnt[(int)(pairs[e] >> 24)], 1);
    __syncthreads();
    int v = cnt[t];
    cur[t] = v;
    __syncthreads();
    for (int off = 1; off < 256; off <<= 1) {
        int x = (t >= off) ? cur[t - off] : 0;
        __syncthreads();
        cur[t] += x;
        __syncthreads();
    }
    int excl = cur[t] - v;
    int node = node0 + t;
    if (node < NODES) row_ptr[node] = pbeg + excl;
    cur[t] = excl;
    __syncthreads();
    if (n <= LMAX) {
        for (int e = pbeg + t; e < pend; e += 256) {
            unsigned p = pairs[e];
            int pos = atomicAdd(&cur[(int)(p >> 24)], 1);
            stage[pos] = (int)(p & 0xFFFFFFu);
        }
        __syncthreads();
        for (int i = t; i < n; i += 256) src_sorted[pbeg + i] = stage[i];
    } else {
        for (int e = pbeg + t; e < pend; e += 256) {
            unsigned p = pairs[e];
            int pos = atomicAdd(&cur[(int)(p >> 24)], 1);
            src_sorted[pbeg + pos] = (int)(p & 0xFFFFFFu);
        }
    }
}

// ---------------- conversions (features->bf16+fp8, weights->bf16^T) ----------------

__global__ void conv_kernel(const float* __restrict__ in, unsigned short* __restrict__ outb,
                            unsigned char* __restrict__ outq, int n4,
                            const float* __restrict__ W1s, const float* __restrict__ W1n,
                            const float* __restrict__ W2s, const float* __restrict__ W2n,
                            unsigned short* __restrict__ Wt1s, unsigned short* __restrict__ Wt1n,
                            unsigned short* __restrict__ Wt2s, unsigned short* __restrict__ Wt2n) {
    int i = blockIdx.x * 256 + threadIdx.x;
    if (i < n4) {
        float4 v = reinterpret_cast<const float4*>(in)[i];
        uint2 o;
        o.x = (unsigned)f2b(v.x) | ((unsigned)f2b(v.y) << 16);
        o.y = (unsigned)f2b(v.z) | ((unsigned)f2b(v.w) << 16);
        reinterpret_cast<uint2*>(outb)[i] = o;
        int pk = __builtin_amdgcn_cvt_pk_fp8_f32(v.x, v.y, 0, false);
        pk = __builtin_amdgcn_cvt_pk_fp8_f32(v.z, v.w, pk, true);
        reinterpret_cast<unsigned*>(outq)[i] = (unsigned)pk;
    }
    if (i < 16384) {
        int k = i >> 7, n = i & 127;
        Wt1s[n * 128 + k] = f2b(W1s[i]);
        Wt1n[n * 128 + k] = f2b(W1n[i]);
    }
    if (i < 8192) {
        int k = i >> 6, n = i & 63;
        Wt2s[n * 128 + k] = f2b(W2s[i]);
        Wt2n[n * 128 + k] = f2b(W2n[i]);
    }
}

// ---------------- Mean aggregation, fp8 gather ----------------
// agg128: one wave/node; 16 lanes/row x 8B fp8 (8 feats), 4 groups, unroll 2.

__global__ __launch_bounds__(256) void agg128_fp8(
    const unsigned char* __restrict__ xq, const int* __restrict__ row_ptr,
    const int* __restrict__ srcs, unsigned short* __restrict__ out) {
    int w = (blockIdx.x * 256 + threadIdx.x) >> 6;
    int lane = threadIdx.x & 63;
    if (w >= NODES) return;
    int g = lane >> 4;
    int sl = lane & 15;
    int beg = row_ptr[w], end = row_ptr[w + 1];

    float a0[8], a1[8];
#pragma unroll
    for (int i = 0; i < 8; ++i) { a0[i] = 0.f; a1[i] = 0.f; }

    const unsigned char* xs = xq + sl * 8;
    int e = beg + g;
    for (; e + 4 < end; e += 8) {
        int s0 = srcs[e];
        int s1 = srcs[e + 4];
        uint2 v0 = *reinterpret_cast<const uint2*>(xs + (size_t)s0 * 128);
        uint2 v1 = *reinterpret_cast<const uint2*>(xs + (size_t)s1 * 128);
        add_fp8x8(a0, v0);
        add_fp8x8(a1, v1);
    }
    if (e < end) {
        int s0 = srcs[e];
        uint2 v0 = *reinterpret_cast<const uint2*>(xs + (size_t)s0 * 128);
        add_fp8x8(a0, v0);
    }
#pragma unroll
    for (int i = 0; i < 8; ++i) {
        float s = a0[i] + a1[i];
        s += __shfl_xor(s, 16, 64);
        s += __shfl_xor(s, 32, 64);
        a0[i] = s;
    }
    if (g == 0) {
        float inv = 1.0f / fmaxf((float)(end - beg), 1.0f);
        uint4 o;
        o.x = (unsigned)f2b(a0[0] * inv) | ((unsigned)f2b(a0[1] * inv) << 16);
        o.y = (unsigned)f2b(a0[2] * inv) | ((unsigned)f2b(a0[3] * inv) << 16);
        o.z = (unsigned)f2b(a0[4] * inv) | ((unsigned)f2b(a0[5] * inv) << 16);
        o.w = (unsigned)f2b(a0[6] * inv) | ((unsigned)f2b(a0[7] * inv) << 16);
        *reinterpret_cast<uint4*>(out + (size_t)w * 128 + sl * 8) = o;
    }
}

// agg64: one wave/node; 8 lanes/row x 8B fp8, 8 groups, unroll 2. out += mean.
__global__ __launch_bounds__(256) void agg64_add8(
    const unsigned char* __restrict__ xq, const int* __restrict__ row_ptr,
    const int* __restrict__ srcs, float* __restrict__ out) {
    int w = (blockIdx.x * 256 + threadIdx.x) >> 6;
    int lane = threadIdx.x & 63;
    if (w >= NODES) return;
    int g = lane >> 3;
    int sl = lane & 7;
    int beg = row_ptr[w], end = row_ptr[w + 1];

    float a0[8], a1[8];
#pragma unroll
    for (int i = 0; i < 8; ++i) { a0[i] = 0.f; a1[i] = 0.f; }

    const unsigned char* xs = xq + sl * 8;
    int e = beg + g;
    for (; e + 8 < end; e += 16) {
        int s0 = srcs[e];
        int s1 = srcs[e + 8];
        uint2 v0 = *reinterpret_cast<const uint2*>(xs + (size_t)s0 * 64);
        uint2 v1 = *reinterpret_cast<const uint2*>(xs + (size_t)s1 * 64);
        add_fp8x8(a0, v0);
        add_fp8x8(a1, v1);
    }
    if (e < end) {
        int s0 = srcs[e];
        uint2 v0 = *reinterpret_cast<const uint2*>(xs + (size_t)s0 * 64);
        add_fp8x8(a0, v0);
    }
#pragma unroll
    for (int i = 0; i < 8; ++i) {
        float s = a0[i] + a1[i];
        s += __shfl_xor(s, 8, 64);
        s += __shfl_xor(s, 16, 64);
        s += __shfl_xor(s, 32, 64);
        a0[i] = s;
    }
    if (g == 0) {
        float inv = 1.0f / fmaxf((float)(end - beg), 1.0f);
        float* op = out + (size_t)w * 64 + sl * 8;
        float4 p0 = *reinterpret_cast<float4*>(op);
        float4 p1 = *reinterpret_cast<float4*>(op + 4);
        p0.x += a0[0] * inv; p0.y += a0[1] * inv;
        p0.z += a0[2] * inv; p0.w += a0[3] * inv;
        p1.x += a0[4] * inv; p1.y += a0[5] * inv;
        p1.z += a0[6] * inv; p1.w += a0[7] * inv;
        *reinterpret_cast<float4*>(op) = p0;
        *reinterpret_cast<float4*>(op + 4) = p1;
    }
}

// ---------------- Fused MLP (persistent B in regs, x1 via LDS only) ----------------

__global__ __launch_bounds__(256, 2) void fused_mlp(
    const unsigned short* __restrict__ featb, const unsigned short* __restrict__ agg,
    const unsigned short* __restrict__ Wt1s, const unsigned short* __restrict__ Wt1n,
    const float* __restrict__ b1, const unsigned short* __restrict__ Wt2s,
    const unsigned short* __restrict__ Wt2n, const float* __restrict__ b2,
    unsigned char* __restrict__ x1h8, float* __restrict__ outp) {
    __shared__ __align__(16) unsigned short x1t[32 * 136];
    int wid = threadIdx.x >> 6, lane = threadIdx.x & 63;
    int l15 = lane & 15, quad = lane >> 4;

    bf16x8 B1s[2][4], B1n[2][4];
#pragma unroll
    for (int nt = 0; nt < 2; ++nt) {
        int col = wid * 32 + nt * 16 + l15;
#pragma unroll
        for (int k = 0; k < 4; ++k) {
            B1s[nt][k] = *reinterpret_cast<const bf16x8*>(Wt1s + (size_t)col * 128 + k * 32 + quad * 8);
            B1n[nt][k] = *reinterpret_cast<const bf16x8*>(Wt1n + (size_t)col * 128 + k * 32 + quad * 8);
        }
    }
    bf16x8 B2s[4], B2n[4];
    {
        int col2 = wid * 16 + l15;
#pragma unroll
        for (int k = 0; k < 4; ++k) {
            B2s[k] = *reinterpret_cast<const bf16x8*>(Wt2s + (size_t)col2 * 128 + k * 32 + quad * 8);
            B2n[k] = *reinterpret_cast<const bf16x8*>(Wt2n + (size_t)col2 * 128 + k * 32 + quad * 8);
        }
    }
    float bv1[2];
    bv1[0] = b1[wid * 32 + l15];
    bv1[1] = b1[wid * 32 + 16 + l15];
    float bv2 = b2[wid * 16 + l15];

    for (int c = blockIdx.x; c < MCHUNKS; c += gridDim.x) {
        int rbase = c * 32;
        bf16x8 Af[2][4], Aa[2][4];
#pragma unroll
        for (int rg = 0; rg < 2; ++rg) {
            int r = rbase + rg * 16 + l15;
            if (r >= NODES) r = NODES - 1;
            const unsigned short* fp = featb + (size_t)r * 128 + quad * 8;
            const unsigned short* ap = agg + (size_t)r * 128 + quad * 8;
#pragma unroll
            for (int k = 0; k < 4; ++k) {
                Af[rg][k] = *reinterpret_cast<const bf16x8*>(fp + k * 32);
                Aa[rg][k] = *reinterpret_cast<const bf16x8*>(ap + k * 32);
            }
        }
        f32x4 acc[2][2];
#pragma unroll
        for (int rg = 0; rg < 2; ++rg)
#pragma unroll
            for (int nt = 0; nt < 2; ++nt) acc[rg][nt] = {0.f, 0.f, 0.f, 0.f};
#pragma unroll
        for (int k = 0; k < 4; ++k)
#pragma unroll
            for (int nt = 0; nt < 2; ++nt)
#pragma unroll
                for (int rg = 0; rg < 2; ++rg) {
                    acc[rg][nt] = __builtin_amdgcn_mfma_f32_16x16x32_bf16(Af[rg][k], B1s[nt][k], acc[rg][nt], 0, 0, 0);
                    acc[rg][nt] = __builtin_amdgcn_mfma_f32_16x16x32_bf16(Aa[rg][k], B1n[nt][k], acc[rg][nt], 0, 0, 0);
                }
#pragma unroll
        for (int nt = 0; nt < 2; ++nt)
#pragma unroll
            for (int rg = 0; rg < 2; ++rg)
#pragma unroll
                for (int rr = 0; rr < 4; ++rr) {
                    float v = fmaxf(acc[rg][nt][rr] + bv1[nt], 0.f);
                    x1t[(rg * 16 + quad * 4 + rr) * 136 + wid * 32 + nt * 16 + l15] = f2b(v);
                }
        __syncthreads();
        f32x4 acc2s[2], acc2n[2];
#pragma unroll
        for (int rg = 0; rg < 2; ++rg) { acc2s[rg] = {0.f, 0.f, 0.f, 0.f}; acc2n[rg] = {0.f, 0.f, 0.f, 0.f}; }
#pragma unroll
        for (int k = 0; k < 4; ++k)
#pragma unroll
            for (int rg = 0; rg < 2; ++rg) {
                bf16x8 a = *reinterpret_cast<const bf16x8*>(&x1t[(rg * 16 + l15) * 136 + k * 32 + quad * 8]);
                acc2s[rg] = __builtin_amdgcn_mfma_f32_16x16x32_bf16(a, B2s[k], acc2s[rg], 0, 0, 0);
                acc2n[rg] = __builtin_amdgcn_mfma_f32_16x16x32_bf16(a, B2n[k], acc2n[rg], 0, 0, 0);
            }
        int col2 = wid * 16 + l15;
#pragma unroll
        for (int rg = 0; rg < 2; ++rg)
#pragma unroll
            for (int rr = 0; rr < 4; ++rr) {
                int row = rbase + rg * 16 + quad * 4 + rr;
                if (row < NODES) {
                    float vn = acc2n[rg][rr];
                    int pk = __builtin_amdgcn_cvt_pk_fp8_f32(vn, vn, 0, false);
                    x1h8[(size_t)row * 64 + col2] = (unsigned char)(pk & 0xFF);
                    outp[(size_t)row * 64 + col2] = acc2s[rg][rr] + bv2;
                }
            }
        __syncthreads();
    }
}

// ---------------- launch ----------------

extern "C" void kernel_launch(void* const* d_in, const int* in_sizes, int n_in,
                              void* d_out, int out_size, void* d_ws, size_t ws_size,
                              hipStream_t stream) {
    const float* features = (const float*)d_in[0];
    const int* esrc = (const int*)d_in[1];
    const int* edst = (const int*)d_in[2];
    const float* W1s = (const float*)d_in[3];
    const float* W1n = (const float*)d_in[4];
    const float* b1  = (const float*)d_in[5];
    const float* W2s = (const float*)d_in[6];
    const float* W2n = (const float*)d_in[7];
    const float* b2  = (const float*)d_in[8];
    float* out = (float*)d_out;

    char* ws = (char*)d_ws;
    size_t off = 0;
    auto alloc = [&](size_t bytes) {
        void* p = ws + off;
        off += (bytes + 255) & ~(size_t)255;
        return p;
    };
    int* bucket_cnt = (int*)alloc(512 * 4);
    int* bucket_off = (int*)alloc(512 * 4);
    int* gcursor    = (int*)alloc(512 * 4);
    int* row_ptr    = (int*)alloc((size_t)(NODES + 1) * 4);
    int* src_sorted = (int*)alloc((size_t)EDGES * 4);
    unsigned* pairs = (unsigned*)alloc((size_t)EDGES * 4);
    unsigned short* featb = (unsigned short*)alloc((size_t)NODES * 128 * 2);
    unsigned char*  feat8 = (unsigned char*)alloc((size_t)NODES * 128);
    unsigned short* agg1  = (unsigned short*)alloc((size_t)NODES * 128 * 2);
    unsigned char*  x1h8  = (unsigned char*)alloc((size_t)NODES * 64);
    unsigned short* Wt1s  = (unsigned short*)alloc(16384 * 2);
    unsigned short* Wt1n  = (unsigned short*)alloc(16384 * 2);
    unsigned short* Wt2s  = (unsigned short*)alloc(8192 * 2);
    unsigned short* Wt2n  = (unsigned short*)alloc(8192 * 2);

    // conversions (features -> bf16+fp8; weights -> bf16 transposed)
    conv_kernel<<<(NODES * 128 / 4 + 255) / 256, 256, 0, stream>>>(
        features, featb, feat8, NODES * 128 / 4, W1s, W1n, W2s, W2n, Wt1s, Wt1n, Wt2s, Wt2n);

    // CSR build: coarse hist -> bucket scan -> bucket bin -> per-bucket sort
    hipMemsetAsync(bucket_cnt, 0, 512 * 4, stream);
    bhist_kernel<<<(EDGES + 16383) / 16384, 256, 0, stream>>>(edst, bucket_cnt);
    bscan_kernel<<<1, 512, 0, stream>>>(bucket_cnt, bucket_off, gcursor, row_ptr);
    binscat_kernel<<<(EDGES + CHUNK - 1) / CHUNK, 256, 0, stream>>>(esrc, edst, gcursor, pairs);
    localsort_kernel<<<NBUCK, 256, 0, stream>>>(pairs, bucket_off, row_ptr, src_sorted);

    // layer 1 aggregation (fp8 gather -> bf16 agg matrix)
    agg128_fp8<<<(NODES * 64 + 255) / 256, 256, 0, stream>>>(feat8, row_ptr, src_sorted, agg1);

    // fused MLP: x1 in LDS; writes x1h fp8 + out (self part + bias)
    fused_mlp<<<1024, 256, 0, stream>>>(featb, agg1, Wt1s, Wt1n, b1, Wt2s, Wt2n, b2, x1h8, out);

    // out += mean-neigh(x1h)
    agg64_add8<<<(NODES * 64 + 255) / 256, 256, 0, stream>>>(x1h8, row_ptr, src_sorted, out);
}